// Round 7
// baseline (248.210 us; speedup 1.0000x reference)
//
#include <hip/hip_runtime.h>
#include <math.h>

#define T_TOK 4096
#define C_DIM 256
#define EPSF  1e-5f
// hd^-0.5 * log2(e): folded into q-projection weights/bias -> scores in log2 domain
#define SC_QL (0.17677669529663687f * 1.4426950408889634f)

typedef short  bf16x8  __attribute__((ext_vector_type(8)));
typedef float  f32x4   __attribute__((ext_vector_type(4)));
typedef ushort ushort8 __attribute__((ext_vector_type(8)));
typedef unsigned uint4v __attribute__((ext_vector_type(4)));
typedef unsigned uint2v __attribute__((ext_vector_type(2)));

__device__ __forceinline__ short f2bf(float f) {
    unsigned u = __builtin_bit_cast(unsigned, f);
    unsigned r = (u + 0x7FFFu + ((u >> 16) & 1u)) >> 16;
    return (short)r;
}
__device__ __forceinline__ float bf2f(ushort u) {
    return __builtin_bit_cast(float, ((unsigned)u) << 16);
}
// pack two f32 -> bf16 pair (a=low, b=high), round-half-up via v_perm
__device__ __forceinline__ unsigned pk_bf16(float a, float b) {
    const unsigned ua = __builtin_bit_cast(unsigned, a) + 0x8000u;
    const unsigned ub = __builtin_bit_cast(unsigned, b) + 0x8000u;
    return __builtin_amdgcn_perm(ub, ua, 0x07060302u);
}
// single-instruction pack (RNE) for the attention P-matrix
__device__ __forceinline__ unsigned cvtpk_bf16(float a, float b) {
    unsigned r;
    asm("v_cvt_pk_bf16_f32 %0, %1, %2" : "=v"(r) : "v"(a), "v"(b));
    return r;
}
// gfx950 dual-dest lane-group swaps (exchange across lane bit 5 / bit 4)
__device__ __forceinline__ void plswap32(unsigned &a, unsigned &b) {
    asm("v_permlane32_swap_b32 %0, %1" : "+v"(a), "+v"(b));
}
__device__ __forceinline__ void plswap16(unsigned &a, unsigned &b) {
    asm("v_permlane16_swap_b32 %0, %1" : "+v"(a), "+v"(b));
}
template <int CTRL>
__device__ __forceinline__ float dppf(float x) {
    return __builtin_bit_cast(float,
        __builtin_amdgcn_mov_dpp(__builtin_bit_cast(int, x), CTRL, 0xF, 0xF, true));
}
__device__ __forceinline__ float rowsum16(float x) {
    x += dppf<0xB1>(x);
    x += dppf<0x4E>(x);
    x += dppf<0x141>(x);
    x += dppf<0x140>(x);
    return x;
}
// gelu, tanh form via exp2+rcp: v*t/(t+1), t=exp2(v*(2.302208+0.1029431 v^2))
__device__ __forceinline__ float gelu_f(float v) {
    const float u  = v * v;
    const float w2 = fmaf(u, 0.10294310f, 2.30220800f);
    const float t  = __builtin_amdgcn_exp2f(v * w2);
    return v * t * __builtin_amdgcn_rcpf(t + 1.0f);
}
#define MFMA16(a, b, c) __builtin_amdgcn_mfma_f32_16x16x32_bf16(a, b, c, 0, 0, 0)

// ---------------------------------------------------------------------------
// prep: weights f32->bf16 arena only (q-rows of w_qkv/b_qkv scaled). grid 896.
// ---------------------------------------------------------------------------
__global__ __launch_bounds__(256) void prep_kernel(
    const float* __restrict__ w_in, const float* __restrict__ w_qkv,
    const float* __restrict__ w_ap, const float* __restrict__ w_ff1,
    const float* __restrict__ w_ff2, const float* __restrict__ w_out,
    const float* __restrict__ b_qkv, ushort* __restrict__ wbuf,
    float* __restrict__ bqs)
{
    const int gid = blockIdx.x * 256 + threadIdx.x;
    const int e0 = gid * 4;
    const float* src; int off; float sc = 1.f;
    if (e0 < 65536)       { src = w_in;  off = e0; }
    else if (e0 < 262144) { src = w_qkv; off = e0 - 65536; if (off < 65536) sc = SC_QL; }
    else if (e0 < 327680) { src = w_ap;  off = e0 - 262144; }
    else if (e0 < 589824) { src = w_ff1; off = e0 - 327680; }
    else if (e0 < 851968) { src = w_ff2; off = e0 - 589824; }
    else                  { src = w_out; off = e0 - 851968; }
    const float4 v = *(const float4*)(src + off);
    ushort4 o;
    o.x = (ushort)f2bf(v.x * sc); o.y = (ushort)f2bf(v.y * sc);
    o.z = (ushort)f2bf(v.z * sc); o.w = (ushort)f2bf(v.w * sc);
    *(ushort4*)(wbuf + e0) = o;
    if (gid < 192) {
        const float s2 = (gid < 64) ? SC_QL : 1.f;
        float4 b = ((const float4*)b_qkv)[gid];
        b.x *= s2; b.y *= s2; b.z *= s2; b.w *= s2;
        ((float4*)bqs)[gid] = b;
    }
}

// ---------------------------------------------------------------------------
// Fused pre-attention: BN + proj_in + LN1 + QKV. grid 256, block 1024
// (16 waves), 16 tokens per block. Reads x directly (f32 [c][t]), applies
// BN(eval) in regs, writes the transposed bf16 tile straight to LDS.
// Writes ysum = LN1(tok)+tok and qkv bf16.
// ---------------------------------------------------------------------------
__global__ __launch_bounds__(1024) void fused_pre(
    const float* __restrict__ x, const float* __restrict__ bn_g,
    const float* __restrict__ bn_b, const float* __restrict__ bn_m,
    const float* __restrict__ bn_v,
    const ushort* __restrict__ wb_in, const float* __restrict__ b_in,
    const float* __restrict__ ln1_g, const float* __restrict__ ln1_b,
    const ushort* __restrict__ wb_qkv, const float* __restrict__ bqs,
    float* __restrict__ ysum, ushort* __restrict__ qkvb)
{
    __shared__ ushort Atile[16 * 264];
    __shared__ ushort Ytile[16 * 264];
    __shared__ float  red[16][16][2];
    const int t0 = blockIdx.x * 16;
    const int tid = threadIdx.x, wv = tid >> 6, lane = tid & 63;
    const int c = lane & 15, g = lane >> 4;

    {   // BN + transpose: thread (cc, tt-group) reads 4 t of channel cc
        const int cc = tid >> 2;            // 0..255
        const int tt = (tid & 3) * 4;       // 0,4,8,12
        const float a = rsqrtf(bn_v[cc] + EPSF) * bn_g[cc];
        const float d = bn_b[cc] - bn_m[cc] * a;
        const float4 v = *(const float4*)(x + (size_t)cc * T_TOK + t0 + tt);
        Atile[(tt + 0) * 264 + cc] = (ushort)f2bf(fmaf(v.x, a, d));
        Atile[(tt + 1) * 264 + cc] = (ushort)f2bf(fmaf(v.y, a, d));
        Atile[(tt + 2) * 264 + cc] = (ushort)f2bf(fmaf(v.z, a, d));
        Atile[(tt + 3) * 264 + cc] = (ushort)f2bf(fmaf(v.w, a, d));
    }
    __syncthreads();

    // ---- proj_in: wave w -> cols [16w, 16w+16), one frag ----
    f32x4 accp = {};
#pragma unroll
    for (int kc = 0; kc < 8; ++kc) {
        const bf16x8 af = *(const bf16x8*)&Atile[c * 264 + kc * 32 + g * 8];
        const bf16x8 bfv = *(const bf16x8*)(wb_in +
            (size_t)(wv * 16 + c) * 256 + kc * 32 + g * 8);
        accp = MFMA16(af, bfv, accp);
    }
    const int colp = wv * 16 + c;
    {
        const float bb = b_in[colp];
        float vs[4], s1[4], s2[4];
#pragma unroll
        for (int rr = 0; rr < 4; ++rr) {
            const float v = accp[rr] + bb;
            vs[rr] = v; s1[rr] = v; s2[rr] = v * v;
        }
#pragma unroll
        for (int rr = 0; rr < 4; ++rr) { s1[rr] = rowsum16(s1[rr]); s2[rr] = rowsum16(s2[rr]); }
        if (c == 0) {
#pragma unroll
            for (int rr = 0; rr < 4; ++rr) {
                red[wv][4 * g + rr][0] = s1[rr];
                red[wv][4 * g + rr][1] = s2[rr];
            }
        }
        __syncthreads();
        if (tid < 32) {   // stage-2 reduce across 16 waves
            const int row = tid >> 1, j = tid & 1;
            float s = 0.f;
#pragma unroll
            for (int w = 0; w < 16; ++w) s += red[w][row][j];
            red[0][row][j] = s;
        }
        __syncthreads();
        const float gg = ln1_g[colp], lb = ln1_b[colp];
#pragma unroll
        for (int rr = 0; rr < 4; ++rr) {
            const int row = 4 * g + rr;
            const float mu = red[0][row][0] * (1.0f / 256.0f);
            const float var = red[0][row][1] * (1.0f / 256.0f) - mu * mu;
            const float rs = rsqrtf(var + EPSF);
            const float yv = (vs[rr] - mu) * rs * gg + lb;
            ysum[(size_t)(t0 + row) * 256 + colp] = yv + vs[rr];
            Ytile[row * 264 + colp] = (ushort)f2bf(yv);
        }
    }
    __syncthreads();

    // ---- QKV: wave w -> cols [48w, 48w+48), 3 frags ----
    f32x4 accq[3] = {};
#pragma unroll
    for (int kc = 0; kc < 8; ++kc) {
        const bf16x8 af = *(const bf16x8*)&Ytile[c * 264 + kc * 32 + g * 8];
#pragma unroll
        for (int nf = 0; nf < 3; ++nf) {
            const bf16x8 bfv = *(const bf16x8*)(wb_qkv +
                (size_t)(wv * 48 + nf * 16 + c) * 256 + kc * 32 + g * 8);
            accq[nf] = MFMA16(af, bfv, accq[nf]);
        }
    }
#pragma unroll
    for (int nf = 0; nf < 3; ++nf) {
        const int col = wv * 48 + nf * 16 + c;
        const float bb = bqs[col];
#pragma unroll
        for (int rr = 0; rr < 4; ++rr)
            qkvb[(size_t)(t0 + 4 * g + rr) * 768 + col] = (ushort)f2bf(accq[nf][rr] + bb);
    }
}

// ---------------------------------------------------------------------------
// Flash attention, bf16 MFMA, no-max exp2 softmax, split-K over 4 quarters.
// grid=(T/64, HEADS, 4) = 2048 blocks.
// K LDS staging DELETED: K is write-once/read-once in LDS (zero reuse), and
// the A-fragment layout is natively addressable in global — lane (c,g)
// reads 16 contiguous bytes at (kt*64+16f+c)*768 + g*8. K frags are read
// direct from L2 (64KB working set per (h,qrt), shared by 64 q-blocks),
// software-pipelined one iteration ahead (ka/kb ping-pong, static names —
// no runtime-indexed arrays). Halves LDS traffic; LDS 19.4->9.2 KB.
// V staging kept (needs the v_perm transpose). Single barrier per tile.
// ---------------------------------------------------------------------------
#define VTS  72

__device__ __forceinline__ void attn_step(
    const bf16x8 k0, const bf16x8 k1, const bf16x8 k2, const bf16x8 k3,
    const bf16x8 qf, const bf16x8 ones, const ushort* __restrict__ vt,
    const int c, const int g,
    f32x4& oacc0, f32x4& oacc1, f32x4& oaccl)
{
    const f32x4 zz = {0.f, 0.f, 0.f, 0.f};
    const f32x4 s0 = MFMA16(k0, qf, zz);
    const f32x4 s1 = MFMA16(k1, qf, zz);
    const f32x4 s2 = MFMA16(k2, qf, zz);
    const f32x4 s3 = MFMA16(k3, qf, zz);

    // exp2 + pack: lane(c,g) holds P[query=c][key=16f+4g+rr] -> bf16 pairs
    unsigned w00 = cvtpk_bf16(__builtin_amdgcn_exp2f(s0[0]), __builtin_amdgcn_exp2f(s0[1]));
    unsigned w01 = cvtpk_bf16(__builtin_amdgcn_exp2f(s0[2]), __builtin_amdgcn_exp2f(s0[3]));
    unsigned w10 = cvtpk_bf16(__builtin_amdgcn_exp2f(s1[0]), __builtin_amdgcn_exp2f(s1[1]));
    unsigned w11 = cvtpk_bf16(__builtin_amdgcn_exp2f(s1[2]), __builtin_amdgcn_exp2f(s1[3]));
    unsigned w20 = cvtpk_bf16(__builtin_amdgcn_exp2f(s2[0]), __builtin_amdgcn_exp2f(s2[1]));
    unsigned w21 = cvtpk_bf16(__builtin_amdgcn_exp2f(s2[2]), __builtin_amdgcn_exp2f(s2[3]));
    unsigned w30 = cvtpk_bf16(__builtin_amdgcn_exp2f(s3[0]), __builtin_amdgcn_exp2f(s3[1]));
    unsigned w31 = cvtpk_bf16(__builtin_amdgcn_exp2f(s3[2]), __builtin_amdgcn_exp2f(s3[3]));

    // in-register D->A relayout across lane groups g (bits 4-5)
    plswap32(w00, w10); plswap16(w00, w10);
    plswap32(w01, w11); plswap16(w01, w11);
    plswap32(w20, w30); plswap16(w20, w30);
    plswap32(w21, w31); plswap16(w21, w31);
    const uint4v u0 = {w00, w01, w10, w11};
    const uint4v u1 = {w20, w21, w30, w31};
    const bf16x8 pa0 = __builtin_bit_cast(bf16x8, u0);
    const bf16x8 pa1 = __builtin_bit_cast(bf16x8, u1);

    // PV (+ row-sum via ones-MFMA on the otherwise idle matrix pipe)
    const bf16x8 va0 = *(const bf16x8*)&vt[(c)      * VTS + 0 * 32 + g * 8];
    const bf16x8 vb0 = *(const bf16x8*)&vt[(16 + c) * VTS + 0 * 32 + g * 8];
    oacc0 = MFMA16(pa0, va0, oacc0);
    oacc1 = MFMA16(pa0, vb0, oacc1);
    oaccl = MFMA16(pa0, ones, oaccl);
    const bf16x8 va1 = *(const bf16x8*)&vt[(c)      * VTS + 1 * 32 + g * 8];
    const bf16x8 vb1 = *(const bf16x8*)&vt[(16 + c) * VTS + 1 * 32 + g * 8];
    oacc0 = MFMA16(pa1, va1, oacc0);
    oacc1 = MFMA16(pa1, vb1, oacc1);
    oaccl = MFMA16(pa1, ones, oaccl);
}

__global__ __launch_bounds__(256) void attn_mfma(
    const ushort* __restrict__ qkv, ushort* __restrict__ o1,
    ushort* __restrict__ o2, ushort* __restrict__ o3,
    ushort* __restrict__ o4, float* __restrict__ lpart)
{
    const int h    = blockIdx.y;
    const int q0   = blockIdx.x << 6;
    const int qrt  = blockIdx.z;
    const int tid  = threadIdx.x;
    const int wv   = tid >> 6, lane = tid & 63;
    const int c    = lane & 15, g = lane >> 4;

    __shared__ ushort Vt[2][32 * VTS];

    const bf16x8 qf = *(const bf16x8*)(qkv + (size_t)(q0 + wv * 16 + c) * 768 + h * 32 + g * 8);

    bf16x8 ones;
#pragma unroll
    for (int i = 0; i < 8; ++i) ones[i] = (short)0x3F80;

    f32x4 oacc0 = {0.f, 0.f, 0.f, 0.f};
    f32x4 oacc1 = {0.f, 0.f, 0.f, 0.f};
    f32x4 oaccl = {0.f, 0.f, 0.f, 0.f};

    const int vp = tid & 31, vd = (tid >> 5) * 4;
    const ushort* kbase = qkv + 256 + h * 32;
    const ushort* vbase = qkv + 512 + h * 32;
    const ushort* kpl   = kbase + (size_t)c * 768 + g * 8;   // per-lane K base

    const int kt0 = qrt * 16, kt1 = kt0 + 16;

#define KLOAD(d0, d1, d2, d3, kt_)                                            \
    d0 = *(const bf16x8*)(kpl + ((size_t)(kt_) * 64 +  0) * 768);             \
    d1 = *(const bf16x8*)(kpl + ((size_t)(kt_) * 64 + 16) * 768);             \
    d2 = *(const bf16x8*)(kpl + ((size_t)(kt_) * 64 + 32) * 768);             \
    d3 = *(const bf16x8*)(kpl + ((size_t)(kt_) * 64 + 48) * 768)

#define VSTAGE(buf_, va_, vb_) {                                              \
    unsigned* vtp = (unsigned*)&Vt[buf_][0];                                  \
    vtp[(vd + 0) * (VTS / 2) + vp] = __builtin_amdgcn_perm(vb_.x, va_.x, 0x05040100u); \
    vtp[(vd + 1) * (VTS / 2) + vp] = __builtin_amdgcn_perm(vb_.x, va_.x, 0x07060302u); \
    vtp[(vd + 2) * (VTS / 2) + vp] = __builtin_amdgcn_perm(vb_.y, va_.y, 0x05040100u); \
    vtp[(vd + 3) * (VTS / 2) + vp] = __builtin_amdgcn_perm(vb_.y, va_.y, 0x07060302u); }

#define VPREF(kt_) {                                                          \
    vpre0 = *(const uint2v*)(vbase + ((size_t)(kt_) * 64 + 2 * vp) * 768 + vd);       \
    vpre1 = *(const uint2v*)(vbase + ((size_t)(kt_) * 64 + 2 * vp + 1) * 768 + vd); }

    bf16x8 ka0, ka1, ka2, ka3, kb0, kb1, kb2, kb3;
    uint2v vpre0, vpre1;
    KLOAD(ka0, ka1, ka2, ka3, kt0);
    {   // stage V tile kt0 directly into buf 0
        const uint2v va = *(const uint2v*)(vbase + ((size_t)kt0 * 64 + 2 * vp) * 768 + vd);
        const uint2v vb = *(const uint2v*)(vbase + ((size_t)kt0 * 64 + 2 * vp + 1) * 768 + vd);
        VSTAGE(0, va, vb);
    }
    VPREF(kt0 + 1);
    __syncthreads();

    for (int kt = kt0; kt < kt1; kt += 2) {
        // ---- body A: tile kt (V buf 0, K regs ka) ----
        KLOAD(kb0, kb1, kb2, kb3, kt + 1);        // kt+1 < kt1 (16 tiles, even)
        VSTAGE(1, vpre0, vpre1);
        if (kt + 2 < kt1) VPREF(kt + 2);
        attn_step(ka0, ka1, ka2, ka3, qf, ones, &Vt[0][0], c, g, oacc0, oacc1, oaccl);
        __syncthreads();

        // ---- body B: tile kt+1 (V buf 1, K regs kb) ----
        if (kt + 2 < kt1) {
            KLOAD(ka0, ka1, ka2, ka3, kt + 2);
            VSTAGE(0, vpre0, vpre1);
            VPREF(kt + 3);                        // kt+3 <= kt1-1 when kt+2 < kt1
        }
        attn_step(kb0, kb1, kb2, kb3, qf, ones, &Vt[1][0], c, g, oacc0, oacc1, oaccl);
        __syncthreads();
    }

    {
        ushort* ob = (qrt & 2) ? ((qrt & 1) ? o4 : o3) : ((qrt & 1) ? o2 : o1);
        ushort* op = ob + (size_t)(q0 + wv * 16) * 256 + h * 32;
#pragma unroll
        for (int rr = 0; rr < 4; ++rr) {
            op[(4 * g + rr) * 256 + c]      = (ushort)f2bf(oacc0[rr]);
            op[(4 * g + rr) * 256 + 16 + c] = (ushort)f2bf(oacc1[rr]);
        }
        if (c == 0) {
#pragma unroll
            for (int rr = 0; rr < 4; ++rr)
                lpart[(size_t)(q0 + wv * 16 + 4 * g + rr) * 32 + qrt * 8 + h] = oaccl[rr];
        }
    }
#undef KLOAD
#undef VSTAGE
#undef VPREF
}

// ---------------------------------------------------------------------------
// Fused tail: combine O quarters + attn-proj + residuals + LN2 + FF1(gelu)
// + FF2 + residual + proj_out + outer residual — one kernel.
// grid 256, block 1024 (16 waves), 16 tokens per block. LDS 60.4 KB.
// ---------------------------------------------------------------------------
__global__ __launch_bounds__(1024) void fused_tail(
    const ushort* __restrict__ o1, const ushort* __restrict__ o2,
    const ushort* __restrict__ o3, const ushort* __restrict__ o4,
    const float* __restrict__ lpart, const ushort* __restrict__ wb_ap,
    const float* __restrict__ b_ap, const float* __restrict__ ysum,
    const float* __restrict__ ln2_g, const float* __restrict__ ln2_b,
    const ushort* __restrict__ wb_ff1, const float* __restrict__ b_ff1,
    const ushort* __restrict__ wb_ff2, const float* __restrict__ b_ff2,
    const ushort* __restrict__ wb_out, const float* __restrict__ b_out,
    const float* __restrict__ x, float* __restrict__ out)
{
    __shared__ ushort Otile[16 * 264];
    __shared__ ushort Ztile[16 * 264];
    __shared__ ushort Zbig[16 * 1032];
    __shared__ ushort T2tile[16 * 264];
    __shared__ float  red[16][16][2];
    const int t0 = blockIdx.x * 16;
    const int tid = threadIdx.x, wv = tid >> 6, lane = tid & 63;
    const int c = lane & 15, g = lane >> 4;

    {   // combine O quarters (ushort4 per thread)
        const int r = tid >> 6, c0 = (tid & 63) * 4;
        const int h = (tid & 63) >> 3;   // c0>>5: head of these 4 channels
        const float* lp = lpart + (size_t)(t0 + r) * 32;
        const float inv = 1.0f / (lp[h] + lp[8 + h] + lp[16 + h] + lp[24 + h]);
        const size_t idx = (size_t)(t0 + r) * 256 + c0;
        const ushort4 a = *(const ushort4*)(o1 + idx);
        const ushort4 b = *(const ushort4*)(o2 + idx);
        const ushort4 d = *(const ushort4*)(o3 + idx);
        const ushort4 e = *(const ushort4*)(o4 + idx);
        unsigned w[2];
        w[0] = pk_bf16((bf2f(a.x) + bf2f(b.x) + bf2f(d.x) + bf2f(e.x)) * inv,
                       (bf2f(a.y) + bf2f(b.y) + bf2f(d.y) + bf2f(e.y)) * inv);
        w[1] = pk_bf16((bf2f(a.z) + bf2f(b.z) + bf2f(d.z) + bf2f(e.z)) * inv,
                       (bf2f(a.w) + bf2f(b.w) + bf2f(d.w) + bf2f(e.w)) * inv);
        *(ushort4*)&Otile[r * 264 + c0] = *(ushort4*)w;
    }
    __syncthreads();

    // ---- attn-proj: wave w -> cols [16w,16w+16), one frag ----
    f32x4 accp = {};
#pragma unroll
    for (int kc = 0; kc < 8; ++kc) {
        const bf16x8 af = *(const bf16x8*)&Otile[c * 264 + kc * 32 + g * 8];
        const bf16x8 bfv = *(const bf16x8*)(wb_ap +
            (size_t)(wv * 16 + c) * 256 + kc * 32 + g * 8);
        accp = MFMA16(af, bfv, accp);
    }
    const int colp = wv * 16 + c;
    float vsave[4];
    {
        const float bb = b_ap[colp];
        float s1[4], s2[4];
#pragma unroll
        for (int rr = 0; rr < 4; ++rr) {
            const size_t idx = (size_t)(t0 + 4 * g + rr) * 256 + colp;
            const float v = accp[rr] + bb + ysum[idx];
            vsave[rr] = v; s1[rr] = v; s2[rr] = v * v;
        }
#pragma unroll
        for (int rr = 0; rr < 4; ++rr) { s1[rr] = rowsum16(s1[rr]); s2[rr] = rowsum16(s2[rr]); }
        if (c == 0) {
#pragma unroll
            for (int rr = 0; rr < 4; ++rr) {
                red[wv][4 * g + rr][0] = s1[rr];
                red[wv][4 * g + rr][1] = s2[rr];
            }
        }
        __syncthreads();
        if (tid < 32) {
            const int row = tid >> 1, j = tid & 1;
            float s = 0.f;
#pragma unroll
            for (int w = 0; w < 16; ++w) s += red[w][row][j];
            red[0][row][j] = s;
        }
        __syncthreads();
        const float gg = ln2_g[colp], lb = ln2_b[colp];
#pragma unroll
        for (int rr = 0; rr < 4; ++rr) {
            const int row = 4 * g + rr;
            const float mu = red[0][row][0] * (1.0f / 256.0f);
            const float var = red[0][row][1] * (1.0f / 256.0f) - mu * mu;
            const float rs = rsqrtf(var + EPSF);
            const float zv = (vsave[rr] - mu) * rs * gg + lb;
            Ztile[row * 264 + colp] = (ushort)f2bf(zv);
        }
    }
    __syncthreads();

    // ---- FF1 + gelu: wave w -> cols [64w,64w+64), 4 frags -> Zbig (LDS) ----
    {
        f32x4 accf[4] = {};
#pragma unroll
        for (int kc = 0; kc < 8; ++kc) {
            const bf16x8 af = *(const bf16x8*)&Ztile[c * 264 + kc * 32 + g * 8];
#pragma unroll
            for (int nf = 0; nf < 4; ++nf) {
                const bf16x8 bfv = *(const bf16x8*)(wb_ff1 +
                    (size_t)(wv * 64 + nf * 16 + c) * 256 + kc * 32 + g * 8);
                accf[nf] = MFMA16(af, bfv, accf[nf]);
            }
        }
#pragma unroll
        for (int nf = 0; nf < 4; ++nf) {
            const int col = wv * 64 + nf * 16 + c;
            const float bb = b_ff1[col];
#pragma unroll
            for (int rr = 0; rr < 4; ++rr) {
                const float v = gelu_f(accf[nf][rr] + bb);
                Zbig[(4 * g + rr) * 1032 + col] = (ushort)f2bf(v);
            }
        }
    }
    __syncthreads();

    // ---- FF2: wave w -> cols [16w,16w+16), one frag, K=1024 (Zbig LDS) ----
    {
        f32x4 accf = {};
#pragma unroll
        for (int kc = 0; kc < 32; ++kc) {
            const bf16x8 af = *(const bf16x8*)&Zbig[c * 1032 + kc * 32 + g * 8];
            const bf16x8 bfv = *(const bf16x8*)(wb_ff2 +
                (size_t)(wv * 16 + c) * 1024 + kc * 32 + g * 8);
            accf = MFMA16(af, bfv, accf);
        }
        const float bb = b_ff2[colp];
#pragma unroll
        for (int rr = 0; rr < 4; ++rr) {
            const float v = accf[rr] + bb + vsave[rr];
            T2tile[(4 * g + rr) * 264 + colp] = (ushort)f2bf(v);
        }
    }
    __syncthreads();

    // ---- proj_out: wave w -> out rows [16w,16w+16) ----
    f32x4 acco = {};
#pragma unroll
    for (int kc = 0; kc < 8; ++kc) {
        const bf16x8 bfr = *(const bf16x8*)&T2tile[c * 264 + kc * 32 + g * 8]; // B: token=c
        const bf16x8 afr = *(const bf16x8*)(wb_out +
            (size_t)(wv * 16 + c) * 256 + kc * 32 + g * 8);
        acco = MFMA16(afr, bfr, acco);
    }
#pragma unroll
    for (int rr = 0; rr < 4; ++rr) {
        const int och = wv * 16 + 4 * g + rr;
        const size_t idx = (size_t)och * T_TOK + t0 + c;
        out[idx] = acco[rr] + b_out[och] + x[idx];
    }
}

// ---------------------------------------------------------------------------
extern "C" void kernel_launch(void* const* d_in, const int* in_sizes, int n_in,
                              void* d_out, int out_size, void* d_ws, size_t ws_size,
                              hipStream_t stream)
{
    const float* x     = (const float*)d_in[0];
    const float* bn_g  = (const float*)d_in[1];
    const float* bn_b  = (const float*)d_in[2];
    const float* bn_m  = (const float*)d_in[3];
    const float* bn_v  = (const float*)d_in[4];
    const float* w_in  = (const float*)d_in[5];
    const float* b_in  = (const float*)d_in[6];
    const float* ln1_g = (const float*)d_in[7];
    const float* ln1_b = (const float*)d_in[8];
    const float* w_qkv = (const float*)d_in[9];
    const float* b_qkv = (const float*)d_in[10];
    const float* w_ap  = (const float*)d_in[11];
    const float* b_ap  = (const float*)d_in[12];
    const float* ln2_g = (const float*)d_in[13];
    const float* ln2_b = (const float*)d_in[14];
    const float* w_ff1 = (const float*)d_in[15];
    const float* b_ff1 = (const float*)d_in[16];
    const float* w_ff2 = (const float*)d_in[17];
    const float* b_ff2 = (const float*)d_in[18];
    const float* w_out = (const float*)d_in[19];
    const float* b_out = (const float*)d_in[20];
    float* out = (float*)d_out;
    float* ws  = (float*)d_ws;

    const size_t MF = 1u << 20;   // 1M f32 = 4 MB
    float*  ysum   = ws + MF;                           // [1M,2M)
    ushort* qkv_bf = (ushort*)(ws + 3 * MF);            // [3M,4.5M)
    ushort* o1p    = (ushort*)(ws + 6 * MF + MF / 2);   // [6.5M,7M)
    ushort* o2p    = (ushort*)(ws + 7 * MF);            // [7M,7.5M)
    ushort* o3p    = (ushort*)(ws + 7 * MF + MF / 2);   // [7.5M,8M)
    ushort* o4p    = (ushort*)(ws + 8 * MF);            // [8M,8.5M)
    float*  lpart  = ws + 8 * MF + MF / 2;              // [8.5M,+128K f32 = 512KB)
    ushort* wbuf   = (ushort*)(ws + 8 * MF + MF / 2 + 131072);  // weight arena
    const ushort* wb_in  = wbuf;
    const ushort* wb_qkv = wbuf + 65536;
    const ushort* wb_ap  = wbuf + 262144;
    const ushort* wb_ff1 = wbuf + 327680;
    const ushort* wb_ff2 = wbuf + 589824;
    const ushort* wb_out = wbuf + 851968;
    float* bqs = (float*)(wbuf + 917504);

    prep_kernel<<<896, 256, 0, stream>>>(w_in, w_qkv, w_ap, w_ff1, w_ff2, w_out,
                                         b_qkv, wbuf, bqs);
    fused_pre<<<256, 1024, 0, stream>>>(x, bn_g, bn_b, bn_m, bn_v,
                                        wb_in, b_in, ln1_g, ln1_b,
                                        wb_qkv, bqs, ysum, qkv_bf);
    attn_mfma<<<dim3(64, 8, 4), 256, 0, stream>>>(qkv_bf, o1p, o2p, o3p, o4p, lpart);
    fused_tail<<<256, 1024, 0, stream>>>(o1p, o2p, o3p, o4p, lpart, wb_ap, b_ap,
                                         ysum, ln2_g, ln2_b, wb_ff1, b_ff1,
                                         wb_ff2, b_ff2, wb_out, b_out, x, out);
}

// Round 8
// 201.487 us; speedup vs baseline: 1.2319x; 1.2319x over previous
//
#include <hip/hip_runtime.h>
#include <math.h>

#define T_TOK 4096
#define C_DIM 256
#define EPSF  1e-5f
// hd^-0.5 * log2(e): folded into q-projection weights/bias -> scores in log2 domain
#define SC_QL (0.17677669529663687f * 1.4426950408889634f)

typedef short  bf16x8  __attribute__((ext_vector_type(8)));
typedef float  f32x4   __attribute__((ext_vector_type(4)));
typedef ushort ushort8 __attribute__((ext_vector_type(8)));
typedef unsigned uint4v __attribute__((ext_vector_type(4)));
typedef unsigned uint2v __attribute__((ext_vector_type(2)));

__device__ __forceinline__ short f2bf(float f) {
    unsigned u = __builtin_bit_cast(unsigned, f);
    unsigned r = (u + 0x7FFFu + ((u >> 16) & 1u)) >> 16;
    return (short)r;
}
__device__ __forceinline__ float bf2f(ushort u) {
    return __builtin_bit_cast(float, ((unsigned)u) << 16);
}
// pack two f32 -> bf16 pair (a=low, b=high), round-half-up via v_perm
__device__ __forceinline__ unsigned pk_bf16(float a, float b) {
    const unsigned ua = __builtin_bit_cast(unsigned, a) + 0x8000u;
    const unsigned ub = __builtin_bit_cast(unsigned, b) + 0x8000u;
    return __builtin_amdgcn_perm(ub, ua, 0x07060302u);
}
// single-instruction pack (RNE) for the attention P-matrix
__device__ __forceinline__ unsigned cvtpk_bf16(float a, float b) {
    unsigned r;
    asm("v_cvt_pk_bf16_f32 %0, %1, %2" : "=v"(r) : "v"(a), "v"(b));
    return r;
}
// gfx950 dual-dest lane-group swaps (exchange across lane bit 5 / bit 4)
__device__ __forceinline__ void plswap32(unsigned &a, unsigned &b) {
    asm("v_permlane32_swap_b32 %0, %1" : "+v"(a), "+v"(b));
}
__device__ __forceinline__ void plswap16(unsigned &a, unsigned &b) {
    asm("v_permlane16_swap_b32 %0, %1" : "+v"(a), "+v"(b));
}
template <int CTRL>
__device__ __forceinline__ float dppf(float x) {
    return __builtin_bit_cast(float,
        __builtin_amdgcn_mov_dpp(__builtin_bit_cast(int, x), CTRL, 0xF, 0xF, true));
}
__device__ __forceinline__ float rowsum16(float x) {
    x += dppf<0xB1>(x);
    x += dppf<0x4E>(x);
    x += dppf<0x141>(x);
    x += dppf<0x140>(x);
    return x;
}
// gelu, tanh form via exp2+rcp: v*t/(t+1), t=exp2(v*(2.302208+0.1029431 v^2))
__device__ __forceinline__ float gelu_f(float v) {
    const float u  = v * v;
    const float w2 = fmaf(u, 0.10294310f, 2.30220800f);
    const float t  = __builtin_amdgcn_exp2f(v * w2);
    return v * t * __builtin_amdgcn_rcpf(t + 1.0f);
}
#define MFMA16(a, b, c) __builtin_amdgcn_mfma_f32_16x16x32_bf16(a, b, c, 0, 0, 0)

// ---------------------------------------------------------------------------
// prep: weights f32->bf16 arena only (q-rows of w_qkv/b_qkv scaled). grid 896.
// ---------------------------------------------------------------------------
__global__ __launch_bounds__(256) void prep_kernel(
    const float* __restrict__ w_in, const float* __restrict__ w_qkv,
    const float* __restrict__ w_ap, const float* __restrict__ w_ff1,
    const float* __restrict__ w_ff2, const float* __restrict__ w_out,
    const float* __restrict__ b_qkv, ushort* __restrict__ wbuf,
    float* __restrict__ bqs)
{
    const int gid = blockIdx.x * 256 + threadIdx.x;
    const int e0 = gid * 4;
    const float* src; int off; float sc = 1.f;
    if (e0 < 65536)       { src = w_in;  off = e0; }
    else if (e0 < 262144) { src = w_qkv; off = e0 - 65536; if (off < 65536) sc = SC_QL; }
    else if (e0 < 327680) { src = w_ap;  off = e0 - 262144; }
    else if (e0 < 589824) { src = w_ff1; off = e0 - 327680; }
    else if (e0 < 851968) { src = w_ff2; off = e0 - 589824; }
    else                  { src = w_out; off = e0 - 851968; }
    const float4 v = *(const float4*)(src + off);
    ushort4 o;
    o.x = (ushort)f2bf(v.x * sc); o.y = (ushort)f2bf(v.y * sc);
    o.z = (ushort)f2bf(v.z * sc); o.w = (ushort)f2bf(v.w * sc);
    *(ushort4*)(wbuf + e0) = o;
    if (gid < 192) {
        const float s2 = (gid < 64) ? SC_QL : 1.f;
        float4 b = ((const float4*)b_qkv)[gid];
        b.x *= s2; b.y *= s2; b.z *= s2; b.w *= s2;
        ((float4*)bqs)[gid] = b;
    }
}

// ---------------------------------------------------------------------------
// Fused pre-attention: BN + proj_in + LN1 + QKV. grid 256, block 1024
// (16 waves), 16 tokens per block. Reads x directly (f32 [c][t]), applies
// BN(eval) in regs, writes the transposed bf16 tile straight to LDS.
// Writes ysum = LN1(tok)+tok and qkv bf16.
// ---------------------------------------------------------------------------
__global__ __launch_bounds__(1024) void fused_pre(
    const float* __restrict__ x, const float* __restrict__ bn_g,
    const float* __restrict__ bn_b, const float* __restrict__ bn_m,
    const float* __restrict__ bn_v,
    const ushort* __restrict__ wb_in, const float* __restrict__ b_in,
    const float* __restrict__ ln1_g, const float* __restrict__ ln1_b,
    const ushort* __restrict__ wb_qkv, const float* __restrict__ bqs,
    float* __restrict__ ysum, ushort* __restrict__ qkvb)
{
    __shared__ ushort Atile[16 * 264];
    __shared__ ushort Ytile[16 * 264];
    __shared__ float  red[16][16][2];
    const int t0 = blockIdx.x * 16;
    const int tid = threadIdx.x, wv = tid >> 6, lane = tid & 63;
    const int c = lane & 15, g = lane >> 4;

    {   // BN + transpose: thread (cc, tt-group) reads 4 t of channel cc
        const int cc = tid >> 2;            // 0..255
        const int tt = (tid & 3) * 4;       // 0,4,8,12
        const float a = rsqrtf(bn_v[cc] + EPSF) * bn_g[cc];
        const float d = bn_b[cc] - bn_m[cc] * a;
        const float4 v = *(const float4*)(x + (size_t)cc * T_TOK + t0 + tt);
        Atile[(tt + 0) * 264 + cc] = (ushort)f2bf(fmaf(v.x, a, d));
        Atile[(tt + 1) * 264 + cc] = (ushort)f2bf(fmaf(v.y, a, d));
        Atile[(tt + 2) * 264 + cc] = (ushort)f2bf(fmaf(v.z, a, d));
        Atile[(tt + 3) * 264 + cc] = (ushort)f2bf(fmaf(v.w, a, d));
    }
    __syncthreads();

    // ---- proj_in: wave w -> cols [16w, 16w+16), one frag ----
    f32x4 accp = {};
#pragma unroll
    for (int kc = 0; kc < 8; ++kc) {
        const bf16x8 af = *(const bf16x8*)&Atile[c * 264 + kc * 32 + g * 8];
        const bf16x8 bfv = *(const bf16x8*)(wb_in +
            (size_t)(wv * 16 + c) * 256 + kc * 32 + g * 8);
        accp = MFMA16(af, bfv, accp);
    }
    const int colp = wv * 16 + c;
    {
        const float bb = b_in[colp];
        float vs[4], s1[4], s2[4];
#pragma unroll
        for (int rr = 0; rr < 4; ++rr) {
            const float v = accp[rr] + bb;
            vs[rr] = v; s1[rr] = v; s2[rr] = v * v;
        }
#pragma unroll
        for (int rr = 0; rr < 4; ++rr) { s1[rr] = rowsum16(s1[rr]); s2[rr] = rowsum16(s2[rr]); }
        if (c == 0) {
#pragma unroll
            for (int rr = 0; rr < 4; ++rr) {
                red[wv][4 * g + rr][0] = s1[rr];
                red[wv][4 * g + rr][1] = s2[rr];
            }
        }
        __syncthreads();
        if (tid < 32) {   // stage-2 reduce across 16 waves
            const int row = tid >> 1, j = tid & 1;
            float s = 0.f;
#pragma unroll
            for (int w = 0; w < 16; ++w) s += red[w][row][j];
            red[0][row][j] = s;
        }
        __syncthreads();
        const float gg = ln1_g[colp], lb = ln1_b[colp];
#pragma unroll
        for (int rr = 0; rr < 4; ++rr) {
            const int row = 4 * g + rr;
            const float mu = red[0][row][0] * (1.0f / 256.0f);
            const float var = red[0][row][1] * (1.0f / 256.0f) - mu * mu;
            const float rs = rsqrtf(var + EPSF);
            const float yv = (vs[rr] - mu) * rs * gg + lb;
            ysum[(size_t)(t0 + row) * 256 + colp] = yv + vs[rr];
            Ytile[row * 264 + colp] = (ushort)f2bf(yv);
        }
    }
    __syncthreads();

    // ---- QKV: wave w -> cols [48w, 48w+48), 3 frags ----
    f32x4 accq[3] = {};
#pragma unroll
    for (int kc = 0; kc < 8; ++kc) {
        const bf16x8 af = *(const bf16x8*)&Ytile[c * 264 + kc * 32 + g * 8];
#pragma unroll
        for (int nf = 0; nf < 3; ++nf) {
            const bf16x8 bfv = *(const bf16x8*)(wb_qkv +
                (size_t)(wv * 48 + nf * 16 + c) * 256 + kc * 32 + g * 8);
            accq[nf] = MFMA16(af, bfv, accq[nf]);
        }
    }
#pragma unroll
    for (int nf = 0; nf < 3; ++nf) {
        const int col = wv * 48 + nf * 16 + c;
        const float bb = bqs[col];
#pragma unroll
        for (int rr = 0; rr < 4; ++rr)
            qkvb[(size_t)(t0 + 4 * g + rr) * 768 + col] = (ushort)f2bf(accq[nf][rr] + bb);
    }
}

// ---------------------------------------------------------------------------
// Flash attention — REVERTED to the R5-measured-best structure (47.8us):
// K+V double-buffered in LDS, K-staging kr=tid>>2 (4 consecutive lanes = one
// contiguous 64B global segment; global coalescing beats bank micro-layout —
// R4/R6 remaps regressed/were flat), V packed via v_perm. Direct-from-L2 K
// (R7) was 2x WORSE: LDS staging is a reuse-multicast (4KB written once
// serves 4 waves); removing it raised K traffic 16x and saturated L2/TA.
// grid=(T/64, HEADS, 4) = 2048 blocks (8 blocks/CU). P relayout in-register
// via permlane swaps; single barrier per K-tile.
// ---------------------------------------------------------------------------
#define KS   40
#define VTS  72

__global__ __launch_bounds__(256) void attn_mfma(
    const ushort* __restrict__ qkv, ushort* __restrict__ o1,
    ushort* __restrict__ o2, ushort* __restrict__ o3,
    ushort* __restrict__ o4, float* __restrict__ lpart)
{
    const int h    = blockIdx.y;
    const int q0   = blockIdx.x << 6;
    const int qrt  = blockIdx.z;
    const int tid  = threadIdx.x;
    const int wv   = tid >> 6, lane = tid & 63;
    const int c    = lane & 15, g = lane >> 4;

    __shared__ ushort Ks[2][64 * KS];
    __shared__ ushort Vt[2][32 * VTS];

    const bf16x8 qf = *(const bf16x8*)(qkv + (size_t)(q0 + wv * 16 + c) * 768 + h * 32 + g * 8);

    bf16x8 ones;
#pragma unroll
    for (int i = 0; i < 8; ++i) ones[i] = (short)0x3F80;

    f32x4 oacc0 = {0.f, 0.f, 0.f, 0.f};
    f32x4 oacc1 = {0.f, 0.f, 0.f, 0.f};
    f32x4 oaccl = {0.f, 0.f, 0.f, 0.f};

    const int kr = tid >> 2, kc = (tid & 3) * 8;
    const int vp = tid & 31, vd = (tid >> 5) * 4;
    const ushort* kbase = qkv + 256 + h * 32;
    const ushort* vbase = qkv + 512 + h * 32;

    const int kt0 = qrt * 16, kt1 = kt0 + 16;

    {   // prologue: stage tile kt0 directly into buf 0
        const ushort8 kv = *(const ushort8*)(kbase + ((size_t)kt0 * 64 + kr) * 768 + kc);
        const uint2v va = *(const uint2v*)(vbase + ((size_t)kt0 * 64 + 2 * vp) * 768 + vd);
        const uint2v vb = *(const uint2v*)(vbase + ((size_t)kt0 * 64 + 2 * vp + 1) * 768 + vd);
        *(ushort8*)&Ks[0][kr * KS + kc] = kv;
        unsigned* vtp = (unsigned*)&Vt[0][0];
        vtp[(vd + 0) * (VTS / 2) + vp] = __builtin_amdgcn_perm(vb.x, va.x, 0x05040100u);
        vtp[(vd + 1) * (VTS / 2) + vp] = __builtin_amdgcn_perm(vb.x, va.x, 0x07060302u);
        vtp[(vd + 2) * (VTS / 2) + vp] = __builtin_amdgcn_perm(vb.y, va.y, 0x05040100u);
        vtp[(vd + 3) * (VTS / 2) + vp] = __builtin_amdgcn_perm(vb.y, va.y, 0x07060302u);
    }
    // prefetch tile kt0+1 into regs
    ushort8 kpre = *(const ushort8*)(kbase + ((size_t)(kt0 + 1) * 64 + kr) * 768 + kc);
    uint2v vpre0 = *(const uint2v*)(vbase + ((size_t)(kt0 + 1) * 64 + 2 * vp) * 768 + vd);
    uint2v vpre1 = *(const uint2v*)(vbase + ((size_t)(kt0 + 1) * 64 + 2 * vp + 1) * 768 + vd);
    __syncthreads();

    int p = 0;
    for (int kt = kt0; kt < kt1; ++kt) {
        const ushort* ks = &Ks[p][0];
        const ushort* vt = &Vt[p][0];
        // K-frag reads from the active buffer (issue early)
        const bf16x8 k0 = *(const bf16x8*)&ks[(0 * 16 + c) * KS + g * 8];
        const bf16x8 k1 = *(const bf16x8*)&ks[(1 * 16 + c) * KS + g * 8];
        const bf16x8 k2 = *(const bf16x8*)&ks[(2 * 16 + c) * KS + g * 8];
        const bf16x8 k3 = *(const bf16x8*)&ks[(3 * 16 + c) * KS + g * 8];

        // stage tile kt+1 into the inactive buffer; prefetch kt+2
        if (kt + 1 < kt1) {
            *(ushort8*)&Ks[p ^ 1][kr * KS + kc] = kpre;
            unsigned* vtp = (unsigned*)&Vt[p ^ 1][0];
            vtp[(vd + 0) * (VTS / 2) + vp] = __builtin_amdgcn_perm(vpre1.x, vpre0.x, 0x05040100u);
            vtp[(vd + 1) * (VTS / 2) + vp] = __builtin_amdgcn_perm(vpre1.x, vpre0.x, 0x07060302u);
            vtp[(vd + 2) * (VTS / 2) + vp] = __builtin_amdgcn_perm(vpre1.y, vpre0.y, 0x05040100u);
            vtp[(vd + 3) * (VTS / 2) + vp] = __builtin_amdgcn_perm(vpre1.y, vpre0.y, 0x07060302u);
            if (kt + 2 < kt1) {
                const size_t t2 = (size_t)(kt + 2) * 64;
                kpre  = *(const ushort8*)(kbase + (t2 + kr) * 768 + kc);
                vpre0 = *(const uint2v*)(vbase + (t2 + 2 * vp) * 768 + vd);
                vpre1 = *(const uint2v*)(vbase + (t2 + 2 * vp + 1) * 768 + vd);
            }
        }

        const f32x4 zz = {0.f, 0.f, 0.f, 0.f};
        const f32x4 s0 = MFMA16(k0, qf, zz);
        const f32x4 s1 = MFMA16(k1, qf, zz);
        const f32x4 s2 = MFMA16(k2, qf, zz);
        const f32x4 s3 = MFMA16(k3, qf, zz);

        // exp2 + pack: lane(c,g) holds P[query=c][key=16f+4g+rr] -> bf16 pairs
        unsigned w00 = cvtpk_bf16(__builtin_amdgcn_exp2f(s0[0]), __builtin_amdgcn_exp2f(s0[1]));
        unsigned w01 = cvtpk_bf16(__builtin_amdgcn_exp2f(s0[2]), __builtin_amdgcn_exp2f(s0[3]));
        unsigned w10 = cvtpk_bf16(__builtin_amdgcn_exp2f(s1[0]), __builtin_amdgcn_exp2f(s1[1]));
        unsigned w11 = cvtpk_bf16(__builtin_amdgcn_exp2f(s1[2]), __builtin_amdgcn_exp2f(s1[3]));
        unsigned w20 = cvtpk_bf16(__builtin_amdgcn_exp2f(s2[0]), __builtin_amdgcn_exp2f(s2[1]));
        unsigned w21 = cvtpk_bf16(__builtin_amdgcn_exp2f(s2[2]), __builtin_amdgcn_exp2f(s2[3]));
        unsigned w30 = cvtpk_bf16(__builtin_amdgcn_exp2f(s3[0]), __builtin_amdgcn_exp2f(s3[1]));
        unsigned w31 = cvtpk_bf16(__builtin_amdgcn_exp2f(s3[2]), __builtin_amdgcn_exp2f(s3[3]));

        // in-register D->A relayout across lane groups g (bits 4-5)
        plswap32(w00, w10); plswap16(w00, w10);
        plswap32(w01, w11); plswap16(w01, w11);
        plswap32(w20, w30); plswap16(w20, w30);
        plswap32(w21, w31); plswap16(w21, w31);
        const uint4v u0 = {w00, w01, w10, w11};
        const uint4v u1 = {w20, w21, w30, w31};
        const bf16x8 pa0 = __builtin_bit_cast(bf16x8, u0);
        const bf16x8 pa1 = __builtin_bit_cast(bf16x8, u1);

        // PV (+ row-sum via ones-MFMA on the otherwise idle matrix pipe)
        {
            const bf16x8 va0 = *(const bf16x8*)&vt[(c)      * VTS + 0 * 32 + g * 8];
            const bf16x8 vb0 = *(const bf16x8*)&vt[(16 + c) * VTS + 0 * 32 + g * 8];
            oacc0 = MFMA16(pa0, va0, oacc0);
            oacc1 = MFMA16(pa0, vb0, oacc1);
            oaccl = MFMA16(pa0, ones, oaccl);
            const bf16x8 va1 = *(const bf16x8*)&vt[(c)      * VTS + 1 * 32 + g * 8];
            const bf16x8 vb1 = *(const bf16x8*)&vt[(16 + c) * VTS + 1 * 32 + g * 8];
            oacc0 = MFMA16(pa1, va1, oacc0);
            oacc1 = MFMA16(pa1, vb1, oacc1);
            oaccl = MFMA16(pa1, ones, oaccl);
        }
        p ^= 1;
        __syncthreads();   // single barrier per K-tile
    }

    {
        ushort* ob = (qrt & 2) ? ((qrt & 1) ? o4 : o3) : ((qrt & 1) ? o2 : o1);
        ushort* op = ob + (size_t)(q0 + wv * 16) * 256 + h * 32;
#pragma unroll
        for (int rr = 0; rr < 4; ++rr) {
            op[(4 * g + rr) * 256 + c]      = (ushort)f2bf(oacc0[rr]);
            op[(4 * g + rr) * 256 + 16 + c] = (ushort)f2bf(oacc1[rr]);
        }
        if (c == 0) {
#pragma unroll
            for (int rr = 0; rr < 4; ++rr)
                lpart[(size_t)(q0 + wv * 16 + 4 * g + rr) * 32 + qrt * 8 + h] = oaccl[rr];
        }
    }
}

// ---------------------------------------------------------------------------
// Fused tail: combine O quarters + attn-proj + residuals + LN2 + FF1(gelu)
// + FF2 + residual + proj_out + outer residual — one kernel.
// grid 256, block 1024 (16 waves), 16 tokens per block. LDS 60.4 KB.
// T14 latency hiding: ysum loads issued before the first barrier (consumed
// 2 phases later); x residual loads issued before the last barrier.
// ---------------------------------------------------------------------------
__global__ __launch_bounds__(1024) void fused_tail(
    const ushort* __restrict__ o1, const ushort* __restrict__ o2,
    const ushort* __restrict__ o3, const ushort* __restrict__ o4,
    const float* __restrict__ lpart, const ushort* __restrict__ wb_ap,
    const float* __restrict__ b_ap, const float* __restrict__ ysum,
    const float* __restrict__ ln2_g, const float* __restrict__ ln2_b,
    const ushort* __restrict__ wb_ff1, const float* __restrict__ b_ff1,
    const ushort* __restrict__ wb_ff2, const float* __restrict__ b_ff2,
    const ushort* __restrict__ wb_out, const float* __restrict__ b_out,
    const float* __restrict__ x, float* __restrict__ out)
{
    __shared__ ushort Otile[16 * 264];
    __shared__ ushort Ztile[16 * 264];
    __shared__ ushort Zbig[16 * 1032];
    __shared__ ushort T2tile[16 * 264];
    __shared__ float  red[16][16][2];
    const int t0 = blockIdx.x * 16;
    const int tid = threadIdx.x, wv = tid >> 6, lane = tid & 63;
    const int c = lane & 15, g = lane >> 4;
    const int colp = wv * 16 + c;

    {   // combine O quarters (ushort4 per thread)
        const int r = tid >> 6, c0 = (tid & 63) * 4;
        const int h = (tid & 63) >> 3;   // c0>>5: head of these 4 channels
        const float* lp = lpart + (size_t)(t0 + r) * 32;
        const float inv = 1.0f / (lp[h] + lp[8 + h] + lp[16 + h] + lp[24 + h]);
        const size_t idx = (size_t)(t0 + r) * 256 + c0;
        const ushort4 a = *(const ushort4*)(o1 + idx);
        const ushort4 b = *(const ushort4*)(o2 + idx);
        const ushort4 d = *(const ushort4*)(o3 + idx);
        const ushort4 e = *(const ushort4*)(o4 + idx);
        unsigned w[2];
        w[0] = pk_bf16((bf2f(a.x) + bf2f(b.x) + bf2f(d.x) + bf2f(e.x)) * inv,
                       (bf2f(a.y) + bf2f(b.y) + bf2f(d.y) + bf2f(e.y)) * inv);
        w[1] = pk_bf16((bf2f(a.z) + bf2f(b.z) + bf2f(d.z) + bf2f(e.z)) * inv,
                       (bf2f(a.w) + bf2f(b.w) + bf2f(d.w) + bf2f(e.w)) * inv);
        *(ushort4*)&Otile[r * 264 + c0] = *(ushort4*)w;
    }
    // issue ysum loads early — consumed after the AP-MFMA phase (T14)
    float ysv[4];
#pragma unroll
    for (int rr = 0; rr < 4; ++rr)
        ysv[rr] = ysum[(size_t)(t0 + 4 * g + rr) * 256 + colp];
    __syncthreads();

    // ---- attn-proj: wave w -> cols [16w,16w+16), one frag ----
    f32x4 accp = {};
#pragma unroll
    for (int kc = 0; kc < 8; ++kc) {
        const bf16x8 af = *(const bf16x8*)&Otile[c * 264 + kc * 32 + g * 8];
        const bf16x8 bfv = *(const bf16x8*)(wb_ap +
            (size_t)(wv * 16 + c) * 256 + kc * 32 + g * 8);
        accp = MFMA16(af, bfv, accp);
    }
    float vsave[4];
    {
        const float bb = b_ap[colp];
        float s1[4], s2[4];
#pragma unroll
        for (int rr = 0; rr < 4; ++rr) {
            const float v = accp[rr] + bb + ysv[rr];
            vsave[rr] = v; s1[rr] = v; s2[rr] = v * v;
        }
#pragma unroll
        for (int rr = 0; rr < 4; ++rr) { s1[rr] = rowsum16(s1[rr]); s2[rr] = rowsum16(s2[rr]); }
        if (c == 0) {
#pragma unroll
            for (int rr = 0; rr < 4; ++rr) {
                red[wv][4 * g + rr][0] = s1[rr];
                red[wv][4 * g + rr][1] = s2[rr];
            }
        }
        __syncthreads();
        if (tid < 32) {
            const int row = tid >> 1, j = tid & 1;
            float s = 0.f;
#pragma unroll
            for (int w = 0; w < 16; ++w) s += red[w][row][j];
            red[0][row][j] = s;
        }
        __syncthreads();
        const float gg = ln2_g[colp], lb = ln2_b[colp];
#pragma unroll
        for (int rr = 0; rr < 4; ++rr) {
            const int row = 4 * g + rr;
            const float mu = red[0][row][0] * (1.0f / 256.0f);
            const float var = red[0][row][1] * (1.0f / 256.0f) - mu * mu;
            const float rs = rsqrtf(var + EPSF);
            const float zv = (vsave[rr] - mu) * rs * gg + lb;
            Ztile[row * 264 + colp] = (ushort)f2bf(zv);
        }
    }
    __syncthreads();

    // ---- FF1 + gelu: wave w -> cols [64w,64w+64), 4 frags -> Zbig (LDS) ----
    {
        f32x4 accf[4] = {};
#pragma unroll
        for (int kc = 0; kc < 8; ++kc) {
            const bf16x8 af = *(const bf16x8*)&Ztile[c * 264 + kc * 32 + g * 8];
#pragma unroll
            for (int nf = 0; nf < 4; ++nf) {
                const bf16x8 bfv = *(const bf16x8*)(wb_ff1 +
                    (size_t)(wv * 64 + nf * 16 + c) * 256 + kc * 32 + g * 8);
                accf[nf] = MFMA16(af, bfv, accf[nf]);
            }
        }
#pragma unroll
        for (int nf = 0; nf < 4; ++nf) {
            const int col = wv * 64 + nf * 16 + c;
            const float bb = b_ff1[col];
#pragma unroll
            for (int rr = 0; rr < 4; ++rr) {
                const float v = gelu_f(accf[nf][rr] + bb);
                Zbig[(4 * g + rr) * 1032 + col] = (ushort)f2bf(v);
            }
        }
    }
    __syncthreads();

    // ---- FF2: wave w -> cols [16w,16w+16), one frag, K=1024 (Zbig LDS) ----
    {
        f32x4 accf = {};
#pragma unroll
        for (int kc = 0; kc < 32; ++kc) {
            const bf16x8 af = *(const bf16x8*)&Zbig[c * 1032 + kc * 32 + g * 8];
            const bf16x8 bfv = *(const bf16x8*)(wb_ff2 +
                (size_t)(wv * 16 + c) * 1024 + kc * 32 + g * 8);
            accf = MFMA16(af, bfv, accf);
        }
        const float bb = b_ff2[colp];
#pragma unroll
        for (int rr = 0; rr < 4; ++rr) {
            const float v = accf[rr] + bb + vsave[rr];
            T2tile[(4 * g + rr) * 264 + colp] = (ushort)f2bf(v);
        }
    }
    // issue x residual loads early — consumed in the proj_out epilogue (T14)
    float xres[4];
#pragma unroll
    for (int rr = 0; rr < 4; ++rr)
        xres[rr] = x[(size_t)(wv * 16 + 4 * g + rr) * T_TOK + t0 + c];
    __syncthreads();

    // ---- proj_out: wave w -> out rows [16w,16w+16) ----
    f32x4 acco = {};
#pragma unroll
    for (int kc = 0; kc < 8; ++kc) {
        const bf16x8 bfr = *(const bf16x8*)&T2tile[c * 264 + kc * 32 + g * 8]; // B: token=c
        const bf16x8 afr = *(const bf16x8*)(wb_out +
            (size_t)(wv * 16 + c) * 256 + kc * 32 + g * 8);
        acco = MFMA16(afr, bfr, acco);
    }
#pragma unroll
    for (int rr = 0; rr < 4; ++rr) {
        const int och = wv * 16 + 4 * g + rr;
        const size_t idx = (size_t)och * T_TOK + t0 + c;
        out[idx] = acco[rr] + b_out[och] + xres[rr];
    }
}

// ---------------------------------------------------------------------------
extern "C" void kernel_launch(void* const* d_in, const int* in_sizes, int n_in,
                              void* d_out, int out_size, void* d_ws, size_t ws_size,
                              hipStream_t stream)
{
    const float* x     = (const float*)d_in[0];
    const float* bn_g  = (const float*)d_in[1];
    const float* bn_b  = (const float*)d_in[2];
    const float* bn_m  = (const float*)d_in[3];
    const float* bn_v  = (const float*)d_in[4];
    const float* w_in  = (const float*)d_in[5];
    const float* b_in  = (const float*)d_in[6];
    const float* ln1_g = (const float*)d_in[7];
    const float* ln1_b = (const float*)d_in[8];
    const float* w_qkv = (const float*)d_in[9];
    const float* b_qkv = (const float*)d_in[10];
    const float* w_ap  = (const float*)d_in[11];
    const float* b_ap  = (const float*)d_in[12];
    const float* ln2_g = (const float*)d_in[13];
    const float* ln2_b = (const float*)d_in[14];
    const float* w_ff1 = (const float*)d_in[15];
    const float* b_ff1 = (const float*)d_in[16];
    const float* w_ff2 = (const float*)d_in[17];
    const float* b_ff2 = (const float*)d_in[18];
    const float* w_out = (const float*)d_in[19];
    const float* b_out = (const float*)d_in[20];
    float* out = (float*)d_out;
    float* ws  = (float*)d_ws;

    const size_t MF = 1u << 20;   // 1M f32 = 4 MB
    float*  ysum   = ws + MF;                           // [1M,2M)
    ushort* qkv_bf = (ushort*)(ws + 3 * MF);            // [3M,4.5M)
    ushort* o1p    = (ushort*)(ws + 6 * MF + MF / 2);   // [6.5M,7M)
    ushort* o2p    = (ushort*)(ws + 7 * MF);            // [7M,7.5M)
    ushort* o3p    = (ushort*)(ws + 7 * MF + MF / 2);   // [7.5M,8M)
    ushort* o4p    = (ushort*)(ws + 8 * MF);            // [8M,8.5M)
    float*  lpart  = ws + 8 * MF + MF / 2;              // [8.5M,+128K f32 = 512KB)
    ushort* wbuf   = (ushort*)(ws + 8 * MF + MF / 2 + 131072);  // weight arena
    const ushort* wb_in  = wbuf;
    const ushort* wb_qkv = wbuf + 65536;
    const ushort* wb_ap  = wbuf + 262144;
    const ushort* wb_ff1 = wbuf + 327680;
    const ushort* wb_ff2 = wbuf + 589824;
    const ushort* wb_out = wbuf + 851968;
    float* bqs = (float*)(wbuf + 917504);

    prep_kernel<<<896, 256, 0, stream>>>(w_in, w_qkv, w_ap, w_ff1, w_ff2, w_out,
                                         b_qkv, wbuf, bqs);
    fused_pre<<<256, 1024, 0, stream>>>(x, bn_g, bn_b, bn_m, bn_v,
                                        wb_in, b_in, ln1_g, ln1_b,
                                        wb_qkv, bqs, ysum, qkv_bf);
    attn_mfma<<<dim3(64, 8, 4), 256, 0, stream>>>(qkv_bf, o1p, o2p, o3p, o4p, lpart);
    fused_tail<<<256, 1024, 0, stream>>>(o1p, o2p, o3p, o4p, lpart, wb_ap, b_ap,
                                         ysum, ln2_g, ln2_b, wb_ff1, b_ff1,
                                         wb_ff2, b_ff2, wb_out, b_out, x, out);
}

// Round 9
// 189.087 us; speedup vs baseline: 1.3127x; 1.0656x over previous
//
#include <hip/hip_runtime.h>
#include <math.h>

#define T_TOK 4096
#define C_DIM 256
#define EPSF  1e-5f
// hd^-0.5 * log2(e): folded into q-projection weights/bias -> scores in log2 domain
#define SC_QL (0.17677669529663687f * 1.4426950408889634f)

typedef short  bf16x8  __attribute__((ext_vector_type(8)));
typedef float  f32x4   __attribute__((ext_vector_type(4)));
typedef ushort ushort8 __attribute__((ext_vector_type(8)));
typedef unsigned uint4v __attribute__((ext_vector_type(4)));
typedef unsigned uint2v __attribute__((ext_vector_type(2)));

__device__ __forceinline__ short f2bf(float f) {
    unsigned u = __builtin_bit_cast(unsigned, f);
    unsigned r = (u + 0x7FFFu + ((u >> 16) & 1u)) >> 16;
    return (short)r;
}
__device__ __forceinline__ float bf2f(ushort u) {
    return __builtin_bit_cast(float, ((unsigned)u) << 16);
}
// pack two f32 -> bf16 pair (a=low, b=high), round-half-up via v_perm
__device__ __forceinline__ unsigned pk_bf16(float a, float b) {
    const unsigned ua = __builtin_bit_cast(unsigned, a) + 0x8000u;
    const unsigned ub = __builtin_bit_cast(unsigned, b) + 0x8000u;
    return __builtin_amdgcn_perm(ub, ua, 0x07060302u);
}
// single-instruction pack (RNE) for the attention P-matrix
__device__ __forceinline__ unsigned cvtpk_bf16(float a, float b) {
    unsigned r;
    asm("v_cvt_pk_bf16_f32 %0, %1, %2" : "=v"(r) : "v"(a), "v"(b));
    return r;
}
// gfx950 dual-dest lane-group swaps (exchange across lane bit 5 / bit 4)
__device__ __forceinline__ void plswap32(unsigned &a, unsigned &b) {
    asm("v_permlane32_swap_b32 %0, %1" : "+v"(a), "+v"(b));
}
__device__ __forceinline__ void plswap16(unsigned &a, unsigned &b) {
    asm("v_permlane16_swap_b32 %0, %1" : "+v"(a), "+v"(b));
}
template <int CTRL>
__device__ __forceinline__ float dppf(float x) {
    return __builtin_bit_cast(float,
        __builtin_amdgcn_mov_dpp(__builtin_bit_cast(int, x), CTRL, 0xF, 0xF, true));
}
__device__ __forceinline__ float rowsum16(float x) {
    x += dppf<0xB1>(x);
    x += dppf<0x4E>(x);
    x += dppf<0x141>(x);
    x += dppf<0x140>(x);
    return x;
}
// gelu, tanh form via exp2+rcp: v*t/(t+1), t=exp2(v*(2.302208+0.1029431 v^2))
__device__ __forceinline__ float gelu_f(float v) {
    const float u  = v * v;
    const float w2 = fmaf(u, 0.10294310f, 2.30220800f);
    const float t  = __builtin_amdgcn_exp2f(v * w2);
    return v * t * __builtin_amdgcn_rcpf(t + 1.0f);
}
#define MFMA16(a, b, c) __builtin_amdgcn_mfma_f32_16x16x32_bf16(a, b, c, 0, 0, 0)

// ---------------------------------------------------------------------------
// prep: weights f32->bf16 arena only (q-rows of w_qkv/b_qkv scaled). grid 896.
// ---------------------------------------------------------------------------
__global__ __launch_bounds__(256) void prep_kernel(
    const float* __restrict__ w_in, const float* __restrict__ w_qkv,
    const float* __restrict__ w_ap, const float* __restrict__ w_ff1,
    const float* __restrict__ w_ff2, const float* __restrict__ w_out,
    const float* __restrict__ b_qkv, ushort* __restrict__ wbuf,
    float* __restrict__ bqs)
{
    const int gid = blockIdx.x * 256 + threadIdx.x;
    const int e0 = gid * 4;
    const float* src; int off; float sc = 1.f;
    if (e0 < 65536)       { src = w_in;  off = e0; }
    else if (e0 < 262144) { src = w_qkv; off = e0 - 65536; if (off < 65536) sc = SC_QL; }
    else if (e0 < 327680) { src = w_ap;  off = e0 - 262144; }
    else if (e0 < 589824) { src = w_ff1; off = e0 - 327680; }
    else if (e0 < 851968) { src = w_ff2; off = e0 - 589824; }
    else                  { src = w_out; off = e0 - 851968; }
    const float4 v = *(const float4*)(src + off);
    ushort4 o;
    o.x = (ushort)f2bf(v.x * sc); o.y = (ushort)f2bf(v.y * sc);
    o.z = (ushort)f2bf(v.z * sc); o.w = (ushort)f2bf(v.w * sc);
    *(ushort4*)(wbuf + e0) = o;
    if (gid < 192) {
        const float s2 = (gid < 64) ? SC_QL : 1.f;
        float4 b = ((const float4*)b_qkv)[gid];
        b.x *= s2; b.y *= s2; b.z *= s2; b.w *= s2;
        ((float4*)bqs)[gid] = b;
    }
}

// ---------------------------------------------------------------------------
// Fused pre-attention: BN + proj_in + LN1 + QKV. grid 256, block 1024
// (16 waves), 16 tokens per block. Reads x directly (f32 [c][t]), applies
// BN(eval) in regs, writes the transposed bf16 tile straight to LDS.
// Writes ysum = LN1(tok)+tok and qkv bf16.
// ---------------------------------------------------------------------------
__global__ __launch_bounds__(1024) void fused_pre(
    const float* __restrict__ x, const float* __restrict__ bn_g,
    const float* __restrict__ bn_b, const float* __restrict__ bn_m,
    const float* __restrict__ bn_v,
    const ushort* __restrict__ wb_in, const float* __restrict__ b_in,
    const float* __restrict__ ln1_g, const float* __restrict__ ln1_b,
    const ushort* __restrict__ wb_qkv, const float* __restrict__ bqs,
    float* __restrict__ ysum, ushort* __restrict__ qkvb)
{
    __shared__ ushort Atile[16 * 264];
    __shared__ ushort Ytile[16 * 264];
    __shared__ float  red[16][16][2];
    const int t0 = blockIdx.x * 16;
    const int tid = threadIdx.x, wv = tid >> 6, lane = tid & 63;
    const int c = lane & 15, g = lane >> 4;

    {   // BN + transpose: thread (cc, tt-group) reads 4 t of channel cc
        const int cc = tid >> 2;            // 0..255
        const int tt = (tid & 3) * 4;       // 0,4,8,12
        const float a = rsqrtf(bn_v[cc] + EPSF) * bn_g[cc];
        const float d = bn_b[cc] - bn_m[cc] * a;
        const float4 v = *(const float4*)(x + (size_t)cc * T_TOK + t0 + tt);
        Atile[(tt + 0) * 264 + cc] = (ushort)f2bf(fmaf(v.x, a, d));
        Atile[(tt + 1) * 264 + cc] = (ushort)f2bf(fmaf(v.y, a, d));
        Atile[(tt + 2) * 264 + cc] = (ushort)f2bf(fmaf(v.z, a, d));
        Atile[(tt + 3) * 264 + cc] = (ushort)f2bf(fmaf(v.w, a, d));
    }
    __syncthreads();

    // ---- proj_in: wave w -> cols [16w, 16w+16), one frag ----
    f32x4 accp = {};
#pragma unroll
    for (int kc = 0; kc < 8; ++kc) {
        const bf16x8 af = *(const bf16x8*)&Atile[c * 264 + kc * 32 + g * 8];
        const bf16x8 bfv = *(const bf16x8*)(wb_in +
            (size_t)(wv * 16 + c) * 256 + kc * 32 + g * 8);
        accp = MFMA16(af, bfv, accp);
    }
    const int colp = wv * 16 + c;
    {
        const float bb = b_in[colp];
        float vs[4], s1[4], s2[4];
#pragma unroll
        for (int rr = 0; rr < 4; ++rr) {
            const float v = accp[rr] + bb;
            vs[rr] = v; s1[rr] = v; s2[rr] = v * v;
        }
#pragma unroll
        for (int rr = 0; rr < 4; ++rr) { s1[rr] = rowsum16(s1[rr]); s2[rr] = rowsum16(s2[rr]); }
        if (c == 0) {
#pragma unroll
            for (int rr = 0; rr < 4; ++rr) {
                red[wv][4 * g + rr][0] = s1[rr];
                red[wv][4 * g + rr][1] = s2[rr];
            }
        }
        __syncthreads();
        if (tid < 32) {   // stage-2 reduce across 16 waves
            const int row = tid >> 1, j = tid & 1;
            float s = 0.f;
#pragma unroll
            for (int w = 0; w < 16; ++w) s += red[w][row][j];
            red[0][row][j] = s;
        }
        __syncthreads();
        const float gg = ln1_g[colp], lb = ln1_b[colp];
#pragma unroll
        for (int rr = 0; rr < 4; ++rr) {
            const int row = 4 * g + rr;
            const float mu = red[0][row][0] * (1.0f / 256.0f);
            const float var = red[0][row][1] * (1.0f / 256.0f) - mu * mu;
            const float rs = rsqrtf(var + EPSF);
            const float yv = (vs[rr] - mu) * rs * gg + lb;
            ysum[(size_t)(t0 + row) * 256 + colp] = yv + vs[rr];
            Ytile[row * 264 + colp] = (ushort)f2bf(yv);
        }
    }
    __syncthreads();

    // ---- QKV: wave w -> cols [48w, 48w+48), 3 frags ----
    f32x4 accq[3] = {};
#pragma unroll
    for (int kc = 0; kc < 8; ++kc) {
        const bf16x8 af = *(const bf16x8*)&Ytile[c * 264 + kc * 32 + g * 8];
#pragma unroll
        for (int nf = 0; nf < 3; ++nf) {
            const bf16x8 bfv = *(const bf16x8*)(wb_qkv +
                (size_t)(wv * 48 + nf * 16 + c) * 256 + kc * 32 + g * 8);
            accq[nf] = MFMA16(af, bfv, accq[nf]);
        }
    }
#pragma unroll
    for (int nf = 0; nf < 3; ++nf) {
        const int col = wv * 48 + nf * 16 + c;
        const float bb = bqs[col];
#pragma unroll
        for (int rr = 0; rr < 4; ++rr)
            qkvb[(size_t)(t0 + 4 * g + rr) * 768 + col] = (ushort)f2bf(accq[nf][rr] + bb);
    }
}

// ---------------------------------------------------------------------------
// Flash attention. R5-best staging structure (K+V LDS double-buffered,
// kr=tid>>2 coalesced, v_perm V-pack, single barrier/tile), now with
// TWO Q-fragments per wave (32 queries): K/V frags are read from LDS once
// and reused in-register for both Q halves -> per-MFMA LDS traffic halves,
// and total staging traffic halves (half the blocks). attn is LDS-throughput
// bound (R6/R7 evidence), so this attacks the actual limiting pipe.
// grid=(T/128, HEADS, 4) = 1024 blocks (4/CU). 20 MFMA per K-tile per wave.
// ---------------------------------------------------------------------------
#define KS   40
#define VTS  72

__global__ __launch_bounds__(256) void attn_mfma(
    const ushort* __restrict__ qkv, ushort* __restrict__ o1,
    ushort* __restrict__ o2, ushort* __restrict__ o3,
    ushort* __restrict__ o4, float* __restrict__ lpart)
{
    const int h    = blockIdx.y;
    const int q0   = blockIdx.x << 7;        // 128 queries per block
    const int qrt  = blockIdx.z;
    const int tid  = threadIdx.x;
    const int wv   = tid >> 6, lane = tid & 63;
    const int c    = lane & 15, g = lane >> 4;

    __shared__ ushort Ks[2][64 * KS];
    __shared__ ushort Vt[2][32 * VTS];

    const bf16x8 qfA = *(const bf16x8*)(qkv + (size_t)(q0 + wv * 32 + c) * 768 + h * 32 + g * 8);
    const bf16x8 qfB = *(const bf16x8*)(qkv + (size_t)(q0 + wv * 32 + 16 + c) * 768 + h * 32 + g * 8);

    bf16x8 ones;
#pragma unroll
    for (int i = 0; i < 8; ++i) ones[i] = (short)0x3F80;

    f32x4 oA0 = {0.f, 0.f, 0.f, 0.f}, oA1 = {0.f, 0.f, 0.f, 0.f}, oAl = {0.f, 0.f, 0.f, 0.f};
    f32x4 oB0 = {0.f, 0.f, 0.f, 0.f}, oB1 = {0.f, 0.f, 0.f, 0.f}, oBl = {0.f, 0.f, 0.f, 0.f};

    const int kr = tid >> 2, kc = (tid & 3) * 8;
    const int vp = tid & 31, vd = (tid >> 5) * 4;
    const ushort* kbase = qkv + 256 + h * 32;
    const ushort* vbase = qkv + 512 + h * 32;

    const int kt0 = qrt * 16, kt1 = kt0 + 16;

    {   // prologue: stage tile kt0 directly into buf 0
        const ushort8 kv = *(const ushort8*)(kbase + ((size_t)kt0 * 64 + kr) * 768 + kc);
        const uint2v va = *(const uint2v*)(vbase + ((size_t)kt0 * 64 + 2 * vp) * 768 + vd);
        const uint2v vb = *(const uint2v*)(vbase + ((size_t)kt0 * 64 + 2 * vp + 1) * 768 + vd);
        *(ushort8*)&Ks[0][kr * KS + kc] = kv;
        unsigned* vtp = (unsigned*)&Vt[0][0];
        vtp[(vd + 0) * (VTS / 2) + vp] = __builtin_amdgcn_perm(vb.x, va.x, 0x05040100u);
        vtp[(vd + 1) * (VTS / 2) + vp] = __builtin_amdgcn_perm(vb.x, va.x, 0x07060302u);
        vtp[(vd + 2) * (VTS / 2) + vp] = __builtin_amdgcn_perm(vb.y, va.y, 0x05040100u);
        vtp[(vd + 3) * (VTS / 2) + vp] = __builtin_amdgcn_perm(vb.y, va.y, 0x07060302u);
    }
    // prefetch tile kt0+1 into regs
    ushort8 kpre = *(const ushort8*)(kbase + ((size_t)(kt0 + 1) * 64 + kr) * 768 + kc);
    uint2v vpre0 = *(const uint2v*)(vbase + ((size_t)(kt0 + 1) * 64 + 2 * vp) * 768 + vd);
    uint2v vpre1 = *(const uint2v*)(vbase + ((size_t)(kt0 + 1) * 64 + 2 * vp + 1) * 768 + vd);
    __syncthreads();

    int p = 0;
    for (int kt = kt0; kt < kt1; ++kt) {
        const ushort* ks = &Ks[p][0];
        const ushort* vt = &Vt[p][0];
        // K-frag reads from the active buffer (issue early) — shared by both Q halves
        const bf16x8 k0 = *(const bf16x8*)&ks[(0 * 16 + c) * KS + g * 8];
        const bf16x8 k1 = *(const bf16x8*)&ks[(1 * 16 + c) * KS + g * 8];
        const bf16x8 k2 = *(const bf16x8*)&ks[(2 * 16 + c) * KS + g * 8];
        const bf16x8 k3 = *(const bf16x8*)&ks[(3 * 16 + c) * KS + g * 8];

        // stage tile kt+1 into the inactive buffer; prefetch kt+2
        if (kt + 1 < kt1) {
            *(ushort8*)&Ks[p ^ 1][kr * KS + kc] = kpre;
            unsigned* vtp = (unsigned*)&Vt[p ^ 1][0];
            vtp[(vd + 0) * (VTS / 2) + vp] = __builtin_amdgcn_perm(vpre1.x, vpre0.x, 0x05040100u);
            vtp[(vd + 1) * (VTS / 2) + vp] = __builtin_amdgcn_perm(vpre1.x, vpre0.x, 0x07060302u);
            vtp[(vd + 2) * (VTS / 2) + vp] = __builtin_amdgcn_perm(vpre1.y, vpre0.y, 0x05040100u);
            vtp[(vd + 3) * (VTS / 2) + vp] = __builtin_amdgcn_perm(vpre1.y, vpre0.y, 0x07060302u);
            if (kt + 2 < kt1) {
                const size_t t2 = (size_t)(kt + 2) * 64;
                kpre  = *(const ushort8*)(kbase + (t2 + kr) * 768 + kc);
                vpre0 = *(const uint2v*)(vbase + (t2 + 2 * vp) * 768 + vd);
                vpre1 = *(const uint2v*)(vbase + (t2 + 2 * vp + 1) * 768 + vd);
            }
        }

        const f32x4 zz = {0.f, 0.f, 0.f, 0.f};
        const f32x4 sA0 = MFMA16(k0, qfA, zz);
        const f32x4 sA1 = MFMA16(k1, qfA, zz);
        const f32x4 sA2 = MFMA16(k2, qfA, zz);
        const f32x4 sA3 = MFMA16(k3, qfA, zz);
        const f32x4 sB0 = MFMA16(k0, qfB, zz);
        const f32x4 sB1 = MFMA16(k1, qfB, zz);
        const f32x4 sB2 = MFMA16(k2, qfB, zz);
        const f32x4 sB3 = MFMA16(k3, qfB, zz);

        // exp2 + pack, both Q halves
        unsigned a00 = cvtpk_bf16(__builtin_amdgcn_exp2f(sA0[0]), __builtin_amdgcn_exp2f(sA0[1]));
        unsigned a01 = cvtpk_bf16(__builtin_amdgcn_exp2f(sA0[2]), __builtin_amdgcn_exp2f(sA0[3]));
        unsigned a10 = cvtpk_bf16(__builtin_amdgcn_exp2f(sA1[0]), __builtin_amdgcn_exp2f(sA1[1]));
        unsigned a11 = cvtpk_bf16(__builtin_amdgcn_exp2f(sA1[2]), __builtin_amdgcn_exp2f(sA1[3]));
        unsigned a20 = cvtpk_bf16(__builtin_amdgcn_exp2f(sA2[0]), __builtin_amdgcn_exp2f(sA2[1]));
        unsigned a21 = cvtpk_bf16(__builtin_amdgcn_exp2f(sA2[2]), __builtin_amdgcn_exp2f(sA2[3]));
        unsigned a30 = cvtpk_bf16(__builtin_amdgcn_exp2f(sA3[0]), __builtin_amdgcn_exp2f(sA3[1]));
        unsigned a31 = cvtpk_bf16(__builtin_amdgcn_exp2f(sA3[2]), __builtin_amdgcn_exp2f(sA3[3]));
        unsigned b00 = cvtpk_bf16(__builtin_amdgcn_exp2f(sB0[0]), __builtin_amdgcn_exp2f(sB0[1]));
        unsigned b01 = cvtpk_bf16(__builtin_amdgcn_exp2f(sB0[2]), __builtin_amdgcn_exp2f(sB0[3]));
        unsigned b10 = cvtpk_bf16(__builtin_amdgcn_exp2f(sB1[0]), __builtin_amdgcn_exp2f(sB1[1]));
        unsigned b11 = cvtpk_bf16(__builtin_amdgcn_exp2f(sB1[2]), __builtin_amdgcn_exp2f(sB1[3]));
        unsigned b20 = cvtpk_bf16(__builtin_amdgcn_exp2f(sB2[0]), __builtin_amdgcn_exp2f(sB2[1]));
        unsigned b21 = cvtpk_bf16(__builtin_amdgcn_exp2f(sB2[2]), __builtin_amdgcn_exp2f(sB2[3]));
        unsigned b30 = cvtpk_bf16(__builtin_amdgcn_exp2f(sB3[0]), __builtin_amdgcn_exp2f(sB3[1]));
        unsigned b31 = cvtpk_bf16(__builtin_amdgcn_exp2f(sB3[2]), __builtin_amdgcn_exp2f(sB3[3]));

        // in-register D->A relayout across lane groups g (bits 4-5)
        plswap32(a00, a10); plswap16(a00, a10);
        plswap32(a01, a11); plswap16(a01, a11);
        plswap32(a20, a30); plswap16(a20, a30);
        plswap32(a21, a31); plswap16(a21, a31);
        plswap32(b00, b10); plswap16(b00, b10);
        plswap32(b01, b11); plswap16(b01, b11);
        plswap32(b20, b30); plswap16(b20, b30);
        plswap32(b21, b31); plswap16(b21, b31);
        const uint4v uA0 = {a00, a01, a10, a11};
        const uint4v uA1 = {a20, a21, a30, a31};
        const uint4v uB0 = {b00, b01, b10, b11};
        const uint4v uB1 = {b20, b21, b30, b31};
        const bf16x8 paA0 = __builtin_bit_cast(bf16x8, uA0);
        const bf16x8 paA1 = __builtin_bit_cast(bf16x8, uA1);
        const bf16x8 paB0 = __builtin_bit_cast(bf16x8, uB0);
        const bf16x8 paB1 = __builtin_bit_cast(bf16x8, uB1);

        // PV: V frags loaded once, reused for both Q halves
        {
            const bf16x8 va0 = *(const bf16x8*)&vt[(c)      * VTS + 0 * 32 + g * 8];
            const bf16x8 vb0 = *(const bf16x8*)&vt[(16 + c) * VTS + 0 * 32 + g * 8];
            oA0 = MFMA16(paA0, va0, oA0);
            oA1 = MFMA16(paA0, vb0, oA1);
            oAl = MFMA16(paA0, ones, oAl);
            oB0 = MFMA16(paB0, va0, oB0);
            oB1 = MFMA16(paB0, vb0, oB1);
            oBl = MFMA16(paB0, ones, oBl);
            const bf16x8 va1 = *(const bf16x8*)&vt[(c)      * VTS + 1 * 32 + g * 8];
            const bf16x8 vb1 = *(const bf16x8*)&vt[(16 + c) * VTS + 1 * 32 + g * 8];
            oA0 = MFMA16(paA1, va1, oA0);
            oA1 = MFMA16(paA1, vb1, oA1);
            oAl = MFMA16(paA1, ones, oAl);
            oB0 = MFMA16(paB1, va1, oB0);
            oB1 = MFMA16(paB1, vb1, oB1);
            oBl = MFMA16(paB1, ones, oBl);
        }
        p ^= 1;
        __syncthreads();   // single barrier per K-tile
    }

    {
        ushort* ob = (qrt & 2) ? ((qrt & 1) ? o4 : o3) : ((qrt & 1) ? o2 : o1);
        ushort* op = ob + (size_t)(q0 + wv * 32) * 256 + h * 32;
#pragma unroll
        for (int rr = 0; rr < 4; ++rr) {
            op[(4 * g + rr) * 256 + c]             = (ushort)f2bf(oA0[rr]);
            op[(4 * g + rr) * 256 + 16 + c]        = (ushort)f2bf(oA1[rr]);
            op[(16 + 4 * g + rr) * 256 + c]        = (ushort)f2bf(oB0[rr]);
            op[(16 + 4 * g + rr) * 256 + 16 + c]   = (ushort)f2bf(oB1[rr]);
        }
        if (c == 0) {
#pragma unroll
            for (int rr = 0; rr < 4; ++rr) {
                lpart[(size_t)(q0 + wv * 32 + 4 * g + rr) * 32 + qrt * 8 + h]      = oAl[rr];
                lpart[(size_t)(q0 + wv * 32 + 16 + 4 * g + rr) * 32 + qrt * 8 + h] = oBl[rr];
            }
        }
    }
}

// ---------------------------------------------------------------------------
// Fused tail: combine O quarters + attn-proj + residuals + LN2 + FF1(gelu)
// + FF2 + residual + proj_out + outer residual — one kernel.
// grid 256, block 1024 (16 waves), 16 tokens per block. LDS 60.4 KB.
// FF2 accumulation split into 2 interleaved chains (ILP).
// ---------------------------------------------------------------------------
__global__ __launch_bounds__(1024) void fused_tail(
    const ushort* __restrict__ o1, const ushort* __restrict__ o2,
    const ushort* __restrict__ o3, const ushort* __restrict__ o4,
    const float* __restrict__ lpart, const ushort* __restrict__ wb_ap,
    const float* __restrict__ b_ap, const float* __restrict__ ysum,
    const float* __restrict__ ln2_g, const float* __restrict__ ln2_b,
    const ushort* __restrict__ wb_ff1, const float* __restrict__ b_ff1,
    const ushort* __restrict__ wb_ff2, const float* __restrict__ b_ff2,
    const ushort* __restrict__ wb_out, const float* __restrict__ b_out,
    const float* __restrict__ x, float* __restrict__ out)
{
    __shared__ ushort Otile[16 * 264];
    __shared__ ushort Ztile[16 * 264];
    __shared__ ushort Zbig[16 * 1032];
    __shared__ ushort T2tile[16 * 264];
    __shared__ float  red[16][16][2];
    const int t0 = blockIdx.x * 16;
    const int tid = threadIdx.x, wv = tid >> 6, lane = tid & 63;
    const int c = lane & 15, g = lane >> 4;
    const int colp = wv * 16 + c;

    {   // combine O quarters (ushort4 per thread)
        const int r = tid >> 6, c0 = (tid & 63) * 4;
        const int h = (tid & 63) >> 3;   // c0>>5: head of these 4 channels
        const float* lp = lpart + (size_t)(t0 + r) * 32;
        const float inv = 1.0f / (lp[h] + lp[8 + h] + lp[16 + h] + lp[24 + h]);
        const size_t idx = (size_t)(t0 + r) * 256 + c0;
        const ushort4 a = *(const ushort4*)(o1 + idx);
        const ushort4 b = *(const ushort4*)(o2 + idx);
        const ushort4 d = *(const ushort4*)(o3 + idx);
        const ushort4 e = *(const ushort4*)(o4 + idx);
        unsigned w[2];
        w[0] = pk_bf16((bf2f(a.x) + bf2f(b.x) + bf2f(d.x) + bf2f(e.x)) * inv,
                       (bf2f(a.y) + bf2f(b.y) + bf2f(d.y) + bf2f(e.y)) * inv);
        w[1] = pk_bf16((bf2f(a.z) + bf2f(b.z) + bf2f(d.z) + bf2f(e.z)) * inv,
                       (bf2f(a.w) + bf2f(b.w) + bf2f(d.w) + bf2f(e.w)) * inv);
        *(ushort4*)&Otile[r * 264 + c0] = *(ushort4*)w;
    }
    // issue ysum loads early — consumed after the AP-MFMA phase (T14)
    float ysv[4];
#pragma unroll
    for (int rr = 0; rr < 4; ++rr)
        ysv[rr] = ysum[(size_t)(t0 + 4 * g + rr) * 256 + colp];
    __syncthreads();

    // ---- attn-proj: wave w -> cols [16w,16w+16), one frag ----
    f32x4 accp = {};
#pragma unroll
    for (int kc = 0; kc < 8; ++kc) {
        const bf16x8 af = *(const bf16x8*)&Otile[c * 264 + kc * 32 + g * 8];
        const bf16x8 bfv = *(const bf16x8*)(wb_ap +
            (size_t)(wv * 16 + c) * 256 + kc * 32 + g * 8);
        accp = MFMA16(af, bfv, accp);
    }
    float vsave[4];
    {
        const float bb = b_ap[colp];
        float s1[4], s2[4];
#pragma unroll
        for (int rr = 0; rr < 4; ++rr) {
            const float v = accp[rr] + bb + ysv[rr];
            vsave[rr] = v; s1[rr] = v; s2[rr] = v * v;
        }
#pragma unroll
        for (int rr = 0; rr < 4; ++rr) { s1[rr] = rowsum16(s1[rr]); s2[rr] = rowsum16(s2[rr]); }
        if (c == 0) {
#pragma unroll
            for (int rr = 0; rr < 4; ++rr) {
                red[wv][4 * g + rr][0] = s1[rr];
                red[wv][4 * g + rr][1] = s2[rr];
            }
        }
        __syncthreads();
        if (tid < 32) {
            const int row = tid >> 1, j = tid & 1;
            float s = 0.f;
#pragma unroll
            for (int w = 0; w < 16; ++w) s += red[w][row][j];
            red[0][row][j] = s;
        }
        __syncthreads();
        const float gg = ln2_g[colp], lb = ln2_b[colp];
#pragma unroll
        for (int rr = 0; rr < 4; ++rr) {
            const int row = 4 * g + rr;
            const float mu = red[0][row][0] * (1.0f / 256.0f);
            const float var = red[0][row][1] * (1.0f / 256.0f) - mu * mu;
            const float rs = rsqrtf(var + EPSF);
            const float zv = (vsave[rr] - mu) * rs * gg + lb;
            Ztile[row * 264 + colp] = (ushort)f2bf(zv);
        }
    }
    __syncthreads();

    // ---- FF1 + gelu: wave w -> cols [64w,64w+64), 4 frags -> Zbig (LDS) ----
    {
        f32x4 accf[4] = {};
#pragma unroll
        for (int kc = 0; kc < 8; ++kc) {
            const bf16x8 af = *(const bf16x8*)&Ztile[c * 264 + kc * 32 + g * 8];
#pragma unroll
            for (int nf = 0; nf < 4; ++nf) {
                const bf16x8 bfv = *(const bf16x8*)(wb_ff1 +
                    (size_t)(wv * 64 + nf * 16 + c) * 256 + kc * 32 + g * 8);
                accf[nf] = MFMA16(af, bfv, accf[nf]);
            }
        }
#pragma unroll
        for (int nf = 0; nf < 4; ++nf) {
            const int col = wv * 64 + nf * 16 + c;
            const float bb = b_ff1[col];
#pragma unroll
            for (int rr = 0; rr < 4; ++rr) {
                const float v = gelu_f(accf[nf][rr] + bb);
                Zbig[(4 * g + rr) * 1032 + col] = (ushort)f2bf(v);
            }
        }
    }
    __syncthreads();

    // ---- FF2: wave w -> cols [16w,16w+16), K=1024, 2 interleaved chains ----
    {
        f32x4 acc0 = {}, acc1 = {};
#pragma unroll
        for (int kc = 0; kc < 32; kc += 2) {
            const bf16x8 af0 = *(const bf16x8*)&Zbig[c * 1032 + kc * 32 + g * 8];
            const bf16x8 bf0 = *(const bf16x8*)(wb_ff2 +
                (size_t)(wv * 16 + c) * 1024 + kc * 32 + g * 8);
            acc0 = MFMA16(af0, bf0, acc0);
            const bf16x8 af1 = *(const bf16x8*)&Zbig[c * 1032 + (kc + 1) * 32 + g * 8];
            const bf16x8 bf1 = *(const bf16x8*)(wb_ff2 +
                (size_t)(wv * 16 + c) * 1024 + (kc + 1) * 32 + g * 8);
            acc1 = MFMA16(af1, bf1, acc1);
        }
        const float bb = b_ff2[colp];
#pragma unroll
        for (int rr = 0; rr < 4; ++rr) {
            const float v = acc0[rr] + acc1[rr] + bb + vsave[rr];
            T2tile[(4 * g + rr) * 264 + colp] = (ushort)f2bf(v);
        }
    }
    // issue x residual loads early — consumed in the proj_out epilogue (T14)
    float xres[4];
#pragma unroll
    for (int rr = 0; rr < 4; ++rr)
        xres[rr] = x[(size_t)(wv * 16 + 4 * g + rr) * T_TOK + t0 + c];
    __syncthreads();

    // ---- proj_out: wave w -> out rows [16w,16w+16) ----
    f32x4 acco = {};
#pragma unroll
    for (int kc = 0; kc < 8; ++kc) {
        const bf16x8 bfr = *(const bf16x8*)&T2tile[c * 264 + kc * 32 + g * 8]; // B: token=c
        const bf16x8 afr = *(const bf16x8*)(wb_out +
            (size_t)(wv * 16 + c) * 256 + kc * 32 + g * 8);
        acco = MFMA16(afr, bfr, acco);
    }
#pragma unroll
    for (int rr = 0; rr < 4; ++rr) {
        const int och = wv * 16 + 4 * g + rr;
        const size_t idx = (size_t)och * T_TOK + t0 + c;
        out[idx] = acco[rr] + b_out[och] + xres[rr];
    }
}

// ---------------------------------------------------------------------------
extern "C" void kernel_launch(void* const* d_in, const int* in_sizes, int n_in,
                              void* d_out, int out_size, void* d_ws, size_t ws_size,
                              hipStream_t stream)
{
    const float* x     = (const float*)d_in[0];
    const float* bn_g  = (const float*)d_in[1];
    const float* bn_b  = (const float*)d_in[2];
    const float* bn_m  = (const float*)d_in[3];
    const float* bn_v  = (const float*)d_in[4];
    const float* w_in  = (const float*)d_in[5];
    const float* b_in  = (const float*)d_in[6];
    const float* ln1_g = (const float*)d_in[7];
    const float* ln1_b = (const float*)d_in[8];
    const float* w_qkv = (const float*)d_in[9];
    const float* b_qkv = (const float*)d_in[10];
    const float* w_ap  = (const float*)d_in[11];
    const float* b_ap  = (const float*)d_in[12];
    const float* ln2_g = (const float*)d_in[13];
    const float* ln2_b = (const float*)d_in[14];
    const float* w_ff1 = (const float*)d_in[15];
    const float* b_ff1 = (const float*)d_in[16];
    const float* w_ff2 = (const float*)d_in[17];
    const float* b_ff2 = (const float*)d_in[18];
    const float* w_out = (const float*)d_in[19];
    const float* b_out = (const float*)d_in[20];
    float* out = (float*)d_out;
    float* ws  = (float*)d_ws;

    const size_t MF = 1u << 20;   // 1M f32 = 4 MB
    float*  ysum   = ws + MF;                           // [1M,2M)
    ushort* qkv_bf = (ushort*)(ws + 3 * MF);            // [3M,4.5M)
    ushort* o1p    = (ushort*)(ws + 6 * MF + MF / 2);   // [6.5M,7M)
    ushort* o2p    = (ushort*)(ws + 7 * MF);            // [7M,7.5M)
    ushort* o3p    = (ushort*)(ws + 7 * MF + MF / 2);   // [7.5M,8M)
    ushort* o4p    = (ushort*)(ws + 8 * MF);            // [8M,8.5M)
    float*  lpart  = ws + 8 * MF + MF / 2;              // [8.5M,+128K f32 = 512KB)
    ushort* wbuf   = (ushort*)(ws + 8 * MF + MF / 2 + 131072);  // weight arena
    const ushort* wb_in  = wbuf;
    const ushort* wb_qkv = wbuf + 65536;
    const ushort* wb_ap  = wbuf + 262144;
    const ushort* wb_ff1 = wbuf + 327680;
    const ushort* wb_ff2 = wbuf + 589824;
    const ushort* wb_out = wbuf + 851968;
    float* bqs = (float*)(wbuf + 917504);

    prep_kernel<<<896, 256, 0, stream>>>(w_in, w_qkv, w_ap, w_ff1, w_ff2, w_out,
                                         b_qkv, wbuf, bqs);
    fused_pre<<<256, 1024, 0, stream>>>(x, bn_g, bn_b, bn_m, bn_v,
                                        wb_in, b_in, ln1_g, ln1_b,
                                        wb_qkv, bqs, ysum, qkv_bf);
    attn_mfma<<<dim3(32, 8, 4), 256, 0, stream>>>(qkv_bf, o1p, o2p, o3p, o4p, lpart);
    fused_tail<<<256, 1024, 0, stream>>>(o1p, o2p, o3p, o4p, lpart, wb_ap, b_ap,
                                         ysum, ln2_g, ln2_b, wb_ff1, b_ff1,
                                         wb_ff2, b_ff2, wb_out, b_out, x, out);
}

// Round 10
// 188.855 us; speedup vs baseline: 1.3143x; 1.0012x over previous
//
#include <hip/hip_runtime.h>
#include <math.h>

#define T_TOK 4096
#define C_DIM 256
#define EPSF  1e-5f
// hd^-0.5 * log2(e): folded into q-projection weights/bias -> scores in log2 domain
#define SC_QL (0.17677669529663687f * 1.4426950408889634f)

typedef short  bf16x8  __attribute__((ext_vector_type(8)));
typedef float  f32x4   __attribute__((ext_vector_type(4)));
typedef ushort ushort8 __attribute__((ext_vector_type(8)));
typedef unsigned uint4v __attribute__((ext_vector_type(4)));
typedef unsigned uint2v __attribute__((ext_vector_type(2)));

__device__ __forceinline__ short f2bf(float f) {
    unsigned u = __builtin_bit_cast(unsigned, f);
    unsigned r = (u + 0x7FFFu + ((u >> 16) & 1u)) >> 16;
    return (short)r;
}
__device__ __forceinline__ float bf2f(ushort u) {
    return __builtin_bit_cast(float, ((unsigned)u) << 16);
}
// pack two f32 -> bf16 pair (a=low, b=high), round-half-up via v_perm
__device__ __forceinline__ unsigned pk_bf16(float a, float b) {
    const unsigned ua = __builtin_bit_cast(unsigned, a) + 0x8000u;
    const unsigned ub = __builtin_bit_cast(unsigned, b) + 0x8000u;
    return __builtin_amdgcn_perm(ub, ua, 0x07060302u);
}
// single-instruction pack (RNE) for the attention P-matrix
__device__ __forceinline__ unsigned cvtpk_bf16(float a, float b) {
    unsigned r;
    asm("v_cvt_pk_bf16_f32 %0, %1, %2" : "=v"(r) : "v"(a), "v"(b));
    return r;
}
// gfx950 dual-dest lane-group swaps (exchange across lane bit 5 / bit 4)
__device__ __forceinline__ void plswap32(unsigned &a, unsigned &b) {
    asm("v_permlane32_swap_b32 %0, %1" : "+v"(a), "+v"(b));
}
__device__ __forceinline__ void plswap16(unsigned &a, unsigned &b) {
    asm("v_permlane16_swap_b32 %0, %1" : "+v"(a), "+v"(b));
}
template <int CTRL>
__device__ __forceinline__ float dppf(float x) {
    return __builtin_bit_cast(float,
        __builtin_amdgcn_mov_dpp(__builtin_bit_cast(int, x), CTRL, 0xF, 0xF, true));
}
__device__ __forceinline__ float rowsum16(float x) {
    x += dppf<0xB1>(x);
    x += dppf<0x4E>(x);
    x += dppf<0x141>(x);
    x += dppf<0x140>(x);
    return x;
}
// gelu, tanh form via exp2+rcp: v*t/(t+1), t=exp2(v*(2.302208+0.1029431 v^2))
__device__ __forceinline__ float gelu_f(float v) {
    const float u  = v * v;
    const float w2 = fmaf(u, 0.10294310f, 2.30220800f);
    const float t  = __builtin_amdgcn_exp2f(v * w2);
    return v * t * __builtin_amdgcn_rcpf(t + 1.0f);
}
#define MFMA16(a, b, c) __builtin_amdgcn_mfma_f32_16x16x32_bf16(a, b, c, 0, 0, 0)

// ---------------------------------------------------------------------------
// prep: weights f32->bf16 arena only (q-rows of w_qkv/b_qkv scaled). grid 896.
// ---------------------------------------------------------------------------
__global__ __launch_bounds__(256) void prep_kernel(
    const float* __restrict__ w_in, const float* __restrict__ w_qkv,
    const float* __restrict__ w_ap, const float* __restrict__ w_ff1,
    const float* __restrict__ w_ff2, const float* __restrict__ w_out,
    const float* __restrict__ b_qkv, ushort* __restrict__ wbuf,
    float* __restrict__ bqs)
{
    const int gid = blockIdx.x * 256 + threadIdx.x;
    const int e0 = gid * 4;
    const float* src; int off; float sc = 1.f;
    if (e0 < 65536)       { src = w_in;  off = e0; }
    else if (e0 < 262144) { src = w_qkv; off = e0 - 65536; if (off < 65536) sc = SC_QL; }
    else if (e0 < 327680) { src = w_ap;  off = e0 - 262144; }
    else if (e0 < 589824) { src = w_ff1; off = e0 - 327680; }
    else if (e0 < 851968) { src = w_ff2; off = e0 - 589824; }
    else                  { src = w_out; off = e0 - 851968; }
    const float4 v = *(const float4*)(src + off);
    ushort4 o;
    o.x = (ushort)f2bf(v.x * sc); o.y = (ushort)f2bf(v.y * sc);
    o.z = (ushort)f2bf(v.z * sc); o.w = (ushort)f2bf(v.w * sc);
    *(ushort4*)(wbuf + e0) = o;
    if (gid < 192) {
        const float s2 = (gid < 64) ? SC_QL : 1.f;
        float4 b = ((const float4*)b_qkv)[gid];
        b.x *= s2; b.y *= s2; b.z *= s2; b.w *= s2;
        ((float4*)bqs)[gid] = b;
    }
}

// ---------------------------------------------------------------------------
// Fused pre-attention: BN + proj_in + LN1 + QKV. grid 256, block 1024
// (16 waves), 16 tokens per block. launch_bounds (1024,4) lifts the VGPR cap
// to 128 so weight fragments can be preloaded 8-deep (one L2 latency per
// group of 8 instead of per ~3 — the kernel was serial-latency bound at
// VGPR=28, all pipes <10%).
// ---------------------------------------------------------------------------
__global__ __launch_bounds__(1024, 4) void fused_pre(
    const float* __restrict__ x, const float* __restrict__ bn_g,
    const float* __restrict__ bn_b, const float* __restrict__ bn_m,
    const float* __restrict__ bn_v,
    const ushort* __restrict__ wb_in, const float* __restrict__ b_in,
    const float* __restrict__ ln1_g, const float* __restrict__ ln1_b,
    const ushort* __restrict__ wb_qkv, const float* __restrict__ bqs,
    float* __restrict__ ysum, ushort* __restrict__ qkvb)
{
    __shared__ ushort Atile[16 * 264];
    __shared__ ushort Ytile[16 * 264];
    __shared__ float  red[16][16][2];
    const int t0 = blockIdx.x * 16;
    const int tid = threadIdx.x, wv = tid >> 6, lane = tid & 63;
    const int c = lane & 15, g = lane >> 4;
    const int colp = wv * 16 + c;

    // early: preload proj_in weight frags (global, no dependencies)
    bf16x8 win[8];
    {
        const ushort* wp = wb_in + (size_t)colp * 256 + g * 8;
#pragma unroll
        for (int kc = 0; kc < 8; ++kc) win[kc] = *(const bf16x8*)(wp + kc * 32);
    }

    {   // BN + transpose: thread (cc, tt-group) reads 4 t of channel cc
        const int cc = tid >> 2;            // 0..255
        const int tt = (tid & 3) * 4;       // 0,4,8,12
        const float a = rsqrtf(bn_v[cc] + EPSF) * bn_g[cc];
        const float d = bn_b[cc] - bn_m[cc] * a;
        const float4 v = *(const float4*)(x + (size_t)cc * T_TOK + t0 + tt);
        Atile[(tt + 0) * 264 + cc] = (ushort)f2bf(fmaf(v.x, a, d));
        Atile[(tt + 1) * 264 + cc] = (ushort)f2bf(fmaf(v.y, a, d));
        Atile[(tt + 2) * 264 + cc] = (ushort)f2bf(fmaf(v.z, a, d));
        Atile[(tt + 3) * 264 + cc] = (ushort)f2bf(fmaf(v.w, a, d));
    }
    __syncthreads();

    // ---- proj_in: wave w -> cols [16w, 16w+16), one frag ----
    f32x4 accp = {};
#pragma unroll
    for (int kc = 0; kc < 8; ++kc) {
        const bf16x8 af = *(const bf16x8*)&Atile[c * 264 + kc * 32 + g * 8];
        accp = MFMA16(af, win[kc], accp);
    }
    {
        const float bb = b_in[colp];
        float vs[4], s1[4], s2[4];
#pragma unroll
        for (int rr = 0; rr < 4; ++rr) {
            const float v = accp[rr] + bb;
            vs[rr] = v; s1[rr] = v; s2[rr] = v * v;
        }
#pragma unroll
        for (int rr = 0; rr < 4; ++rr) { s1[rr] = rowsum16(s1[rr]); s2[rr] = rowsum16(s2[rr]); }
        if (c == 0) {
#pragma unroll
            for (int rr = 0; rr < 4; ++rr) {
                red[wv][4 * g + rr][0] = s1[rr];
                red[wv][4 * g + rr][1] = s2[rr];
            }
        }
        __syncthreads();
        if (tid < 32) {   // stage-2 reduce across 16 waves
            const int row = tid >> 1, j = tid & 1;
            float s = 0.f;
#pragma unroll
            for (int w = 0; w < 16; ++w) s += red[w][row][j];
            red[0][row][j] = s;
        }
        __syncthreads();
        const float gg = ln1_g[colp], lb = ln1_b[colp];
#pragma unroll
        for (int rr = 0; rr < 4; ++rr) {
            const int row = 4 * g + rr;
            const float mu = red[0][row][0] * (1.0f / 256.0f);
            const float var = red[0][row][1] * (1.0f / 256.0f) - mu * mu;
            const float rs = rsqrtf(var + EPSF);
            const float yv = (vs[rr] - mu) * rs * gg + lb;
            ysum[(size_t)(t0 + row) * 256 + colp] = yv + vs[rr];
            Ytile[row * 264 + colp] = (ushort)f2bf(yv);
        }
    }
    __syncthreads();

    // ---- QKV: wave w -> cols [48w, 48w+48), 3 frags; weights preloaded
    //      8-deep per output-frag ----
    const ushort* wq = wb_qkv + (size_t)(wv * 48 + c) * 256 + g * 8;
    f32x4 accq[3] = {};
#pragma unroll
    for (int nf = 0; nf < 3; ++nf) {
        bf16x8 wf[8];
#pragma unroll
        for (int kc = 0; kc < 8; ++kc)
            wf[kc] = *(const bf16x8*)(wq + (size_t)nf * 4096 + kc * 32);
#pragma unroll
        for (int kc = 0; kc < 8; ++kc) {
            const bf16x8 af = *(const bf16x8*)&Ytile[c * 264 + kc * 32 + g * 8];
            accq[nf] = MFMA16(af, wf[kc], accq[nf]);
        }
    }
#pragma unroll
    for (int nf = 0; nf < 3; ++nf) {
        const int col = wv * 48 + nf * 16 + c;
        const float bb = bqs[col];
#pragma unroll
        for (int rr = 0; rr < 4; ++rr)
            qkvb[(size_t)(t0 + 4 * g + rr) * 768 + col] = (ushort)f2bf(accq[nf][rr] + bb);
    }
}

// ---------------------------------------------------------------------------
// Flash attention (R9 structure, unchanged): K+V LDS double-buffered,
// kr=tid>>2 coalesced staging, v_perm V-pack, TWO Q-fragments per wave
// (K/V frags read from LDS once, reused for both Q halves).
// grid=(T/128, HEADS, 4) = 1024 blocks. 20 MFMA per K-tile per wave.
// ---------------------------------------------------------------------------
#define KS   40
#define VTS  72

__global__ __launch_bounds__(256) void attn_mfma(
    const ushort* __restrict__ qkv, ushort* __restrict__ o1,
    ushort* __restrict__ o2, ushort* __restrict__ o3,
    ushort* __restrict__ o4, float* __restrict__ lpart)
{
    const int h    = blockIdx.y;
    const int q0   = blockIdx.x << 7;        // 128 queries per block
    const int qrt  = blockIdx.z;
    const int tid  = threadIdx.x;
    const int wv   = tid >> 6, lane = tid & 63;
    const int c    = lane & 15, g = lane >> 4;

    __shared__ ushort Ks[2][64 * KS];
    __shared__ ushort Vt[2][32 * VTS];

    const bf16x8 qfA = *(const bf16x8*)(qkv + (size_t)(q0 + wv * 32 + c) * 768 + h * 32 + g * 8);
    const bf16x8 qfB = *(const bf16x8*)(qkv + (size_t)(q0 + wv * 32 + 16 + c) * 768 + h * 32 + g * 8);

    bf16x8 ones;
#pragma unroll
    for (int i = 0; i < 8; ++i) ones[i] = (short)0x3F80;

    f32x4 oA0 = {0.f, 0.f, 0.f, 0.f}, oA1 = {0.f, 0.f, 0.f, 0.f}, oAl = {0.f, 0.f, 0.f, 0.f};
    f32x4 oB0 = {0.f, 0.f, 0.f, 0.f}, oB1 = {0.f, 0.f, 0.f, 0.f}, oBl = {0.f, 0.f, 0.f, 0.f};

    const int kr = tid >> 2, kc = (tid & 3) * 8;
    const int vp = tid & 31, vd = (tid >> 5) * 4;
    const ushort* kbase = qkv + 256 + h * 32;
    const ushort* vbase = qkv + 512 + h * 32;

    const int kt0 = qrt * 16, kt1 = kt0 + 16;

    {   // prologue: stage tile kt0 directly into buf 0
        const ushort8 kv = *(const ushort8*)(kbase + ((size_t)kt0 * 64 + kr) * 768 + kc);
        const uint2v va = *(const uint2v*)(vbase + ((size_t)kt0 * 64 + 2 * vp) * 768 + vd);
        const uint2v vb = *(const uint2v*)(vbase + ((size_t)kt0 * 64 + 2 * vp + 1) * 768 + vd);
        *(ushort8*)&Ks[0][kr * KS + kc] = kv;
        unsigned* vtp = (unsigned*)&Vt[0][0];
        vtp[(vd + 0) * (VTS / 2) + vp] = __builtin_amdgcn_perm(vb.x, va.x, 0x05040100u);
        vtp[(vd + 1) * (VTS / 2) + vp] = __builtin_amdgcn_perm(vb.x, va.x, 0x07060302u);
        vtp[(vd + 2) * (VTS / 2) + vp] = __builtin_amdgcn_perm(vb.y, va.y, 0x05040100u);
        vtp[(vd + 3) * (VTS / 2) + vp] = __builtin_amdgcn_perm(vb.y, va.y, 0x07060302u);
    }
    // prefetch tile kt0+1 into regs
    ushort8 kpre = *(const ushort8*)(kbase + ((size_t)(kt0 + 1) * 64 + kr) * 768 + kc);
    uint2v vpre0 = *(const uint2v*)(vbase + ((size_t)(kt0 + 1) * 64 + 2 * vp) * 768 + vd);
    uint2v vpre1 = *(const uint2v*)(vbase + ((size_t)(kt0 + 1) * 64 + 2 * vp + 1) * 768 + vd);
    __syncthreads();

    int p = 0;
    for (int kt = kt0; kt < kt1; ++kt) {
        const ushort* ks = &Ks[p][0];
        const ushort* vt = &Vt[p][0];
        // K-frag reads from the active buffer (issue early) — shared by both Q halves
        const bf16x8 k0 = *(const bf16x8*)&ks[(0 * 16 + c) * KS + g * 8];
        const bf16x8 k1 = *(const bf16x8*)&ks[(1 * 16 + c) * KS + g * 8];
        const bf16x8 k2 = *(const bf16x8*)&ks[(2 * 16 + c) * KS + g * 8];
        const bf16x8 k3 = *(const bf16x8*)&ks[(3 * 16 + c) * KS + g * 8];

        // stage tile kt+1 into the inactive buffer; prefetch kt+2
        if (kt + 1 < kt1) {
            *(ushort8*)&Ks[p ^ 1][kr * KS + kc] = kpre;
            unsigned* vtp = (unsigned*)&Vt[p ^ 1][0];
            vtp[(vd + 0) * (VTS / 2) + vp] = __builtin_amdgcn_perm(vpre1.x, vpre0.x, 0x05040100u);
            vtp[(vd + 1) * (VTS / 2) + vp] = __builtin_amdgcn_perm(vpre1.x, vpre0.x, 0x07060302u);
            vtp[(vd + 2) * (VTS / 2) + vp] = __builtin_amdgcn_perm(vpre1.y, vpre0.y, 0x05040100u);
            vtp[(vd + 3) * (VTS / 2) + vp] = __builtin_amdgcn_perm(vpre1.y, vpre0.y, 0x07060302u);
            if (kt + 2 < kt1) {
                const size_t t2 = (size_t)(kt + 2) * 64;
                kpre  = *(const ushort8*)(kbase + (t2 + kr) * 768 + kc);
                vpre0 = *(const uint2v*)(vbase + (t2 + 2 * vp) * 768 + vd);
                vpre1 = *(const uint2v*)(vbase + (t2 + 2 * vp + 1) * 768 + vd);
            }
        }

        const f32x4 zz = {0.f, 0.f, 0.f, 0.f};
        const f32x4 sA0 = MFMA16(k0, qfA, zz);
        const f32x4 sA1 = MFMA16(k1, qfA, zz);
        const f32x4 sA2 = MFMA16(k2, qfA, zz);
        const f32x4 sA3 = MFMA16(k3, qfA, zz);
        const f32x4 sB0 = MFMA16(k0, qfB, zz);
        const f32x4 sB1 = MFMA16(k1, qfB, zz);
        const f32x4 sB2 = MFMA16(k2, qfB, zz);
        const f32x4 sB3 = MFMA16(k3, qfB, zz);

        // exp2 + pack, both Q halves
        unsigned a00 = cvtpk_bf16(__builtin_amdgcn_exp2f(sA0[0]), __builtin_amdgcn_exp2f(sA0[1]));
        unsigned a01 = cvtpk_bf16(__builtin_amdgcn_exp2f(sA0[2]), __builtin_amdgcn_exp2f(sA0[3]));
        unsigned a10 = cvtpk_bf16(__builtin_amdgcn_exp2f(sA1[0]), __builtin_amdgcn_exp2f(sA1[1]));
        unsigned a11 = cvtpk_bf16(__builtin_amdgcn_exp2f(sA1[2]), __builtin_amdgcn_exp2f(sA1[3]));
        unsigned a20 = cvtpk_bf16(__builtin_amdgcn_exp2f(sA2[0]), __builtin_amdgcn_exp2f(sA2[1]));
        unsigned a21 = cvtpk_bf16(__builtin_amdgcn_exp2f(sA2[2]), __builtin_amdgcn_exp2f(sA2[3]));
        unsigned a30 = cvtpk_bf16(__builtin_amdgcn_exp2f(sA3[0]), __builtin_amdgcn_exp2f(sA3[1]));
        unsigned a31 = cvtpk_bf16(__builtin_amdgcn_exp2f(sA3[2]), __builtin_amdgcn_exp2f(sA3[3]));
        unsigned b00 = cvtpk_bf16(__builtin_amdgcn_exp2f(sB0[0]), __builtin_amdgcn_exp2f(sB0[1]));
        unsigned b01 = cvtpk_bf16(__builtin_amdgcn_exp2f(sB0[2]), __builtin_amdgcn_exp2f(sB0[3]));
        unsigned b10 = cvtpk_bf16(__builtin_amdgcn_exp2f(sB1[0]), __builtin_amdgcn_exp2f(sB1[1]));
        unsigned b11 = cvtpk_bf16(__builtin_amdgcn_exp2f(sB1[2]), __builtin_amdgcn_exp2f(sB1[3]));
        unsigned b20 = cvtpk_bf16(__builtin_amdgcn_exp2f(sB2[0]), __builtin_amdgcn_exp2f(sB2[1]));
        unsigned b21 = cvtpk_bf16(__builtin_amdgcn_exp2f(sB2[2]), __builtin_amdgcn_exp2f(sB2[3]));
        unsigned b30 = cvtpk_bf16(__builtin_amdgcn_exp2f(sB3[0]), __builtin_amdgcn_exp2f(sB3[1]));
        unsigned b31 = cvtpk_bf16(__builtin_amdgcn_exp2f(sB3[2]), __builtin_amdgcn_exp2f(sB3[3]));

        // in-register D->A relayout across lane groups g (bits 4-5)
        plswap32(a00, a10); plswap16(a00, a10);
        plswap32(a01, a11); plswap16(a01, a11);
        plswap32(a20, a30); plswap16(a20, a30);
        plswap32(a21, a31); plswap16(a21, a31);
        plswap32(b00, b10); plswap16(b00, b10);
        plswap32(b01, b11); plswap16(b01, b11);
        plswap32(b20, b30); plswap16(b20, b30);
        plswap32(b21, b31); plswap16(b21, b31);
        const uint4v uA0 = {a00, a01, a10, a11};
        const uint4v uA1 = {a20, a21, a30, a31};
        const uint4v uB0 = {b00, b01, b10, b11};
        const uint4v uB1 = {b20, b21, b30, b31};
        const bf16x8 paA0 = __builtin_bit_cast(bf16x8, uA0);
        const bf16x8 paA1 = __builtin_bit_cast(bf16x8, uA1);
        const bf16x8 paB0 = __builtin_bit_cast(bf16x8, uB0);
        const bf16x8 paB1 = __builtin_bit_cast(bf16x8, uB1);

        // PV: V frags loaded once, reused for both Q halves
        {
            const bf16x8 va0 = *(const bf16x8*)&vt[(c)      * VTS + 0 * 32 + g * 8];
            const bf16x8 vb0 = *(const bf16x8*)&vt[(16 + c) * VTS + 0 * 32 + g * 8];
            oA0 = MFMA16(paA0, va0, oA0);
            oA1 = MFMA16(paA0, vb0, oA1);
            oAl = MFMA16(paA0, ones, oAl);
            oB0 = MFMA16(paB0, va0, oB0);
            oB1 = MFMA16(paB0, vb0, oB1);
            oBl = MFMA16(paB0, ones, oBl);
            const bf16x8 va1 = *(const bf16x8*)&vt[(c)      * VTS + 1 * 32 + g * 8];
            const bf16x8 vb1 = *(const bf16x8*)&vt[(16 + c) * VTS + 1 * 32 + g * 8];
            oA0 = MFMA16(paA1, va1, oA0);
            oA1 = MFMA16(paA1, vb1, oA1);
            oAl = MFMA16(paA1, ones, oAl);
            oB0 = MFMA16(paB1, va1, oB0);
            oB1 = MFMA16(paB1, vb1, oB1);
            oBl = MFMA16(paB1, ones, oBl);
        }
        p ^= 1;
        __syncthreads();   // single barrier per K-tile
    }

    {
        ushort* ob = (qrt & 2) ? ((qrt & 1) ? o4 : o3) : ((qrt & 1) ? o2 : o1);
        ushort* op = ob + (size_t)(q0 + wv * 32) * 256 + h * 32;
#pragma unroll
        for (int rr = 0; rr < 4; ++rr) {
            op[(4 * g + rr) * 256 + c]             = (ushort)f2bf(oA0[rr]);
            op[(4 * g + rr) * 256 + 16 + c]        = (ushort)f2bf(oA1[rr]);
            op[(16 + 4 * g + rr) * 256 + c]        = (ushort)f2bf(oB0[rr]);
            op[(16 + 4 * g + rr) * 256 + 16 + c]   = (ushort)f2bf(oB1[rr]);
        }
        if (c == 0) {
#pragma unroll
            for (int rr = 0; rr < 4; ++rr) {
                lpart[(size_t)(q0 + wv * 32 + 4 * g + rr) * 32 + qrt * 8 + h]      = oAl[rr];
                lpart[(size_t)(q0 + wv * 32 + 16 + 4 * g + rr) * 32 + qrt * 8 + h] = oBl[rr];
            }
        }
    }
}

// ---------------------------------------------------------------------------
// Fused tail: combine + attn-proj + LN2 + FF1(gelu) + FF2 + proj_out.
// grid 256, block 1024 (16 waves), 16 tokens per block. LDS 60.4 KB.
// launch_bounds (1024,4): VGPR cap 128 (was 28 -> serial-latency bound,
// all pipes <10%). Weight fragments preloaded 8-deep per group so the
// ~80 L2 weight loads per wave cost ~10 latency rounds instead of ~25.
// ---------------------------------------------------------------------------
__global__ __launch_bounds__(1024, 4) void fused_tail(
    const ushort* __restrict__ o1, const ushort* __restrict__ o2,
    const ushort* __restrict__ o3, const ushort* __restrict__ o4,
    const float* __restrict__ lpart, const ushort* __restrict__ wb_ap,
    const float* __restrict__ b_ap, const float* __restrict__ ysum,
    const float* __restrict__ ln2_g, const float* __restrict__ ln2_b,
    const ushort* __restrict__ wb_ff1, const float* __restrict__ b_ff1,
    const ushort* __restrict__ wb_ff2, const float* __restrict__ b_ff2,
    const ushort* __restrict__ wb_out, const float* __restrict__ b_out,
    const float* __restrict__ x, float* __restrict__ out)
{
    __shared__ ushort Otile[16 * 264];
    __shared__ ushort Ztile[16 * 264];
    __shared__ ushort Zbig[16 * 1032];
    __shared__ ushort T2tile[16 * 264];
    __shared__ float  red[16][16][2];
    const int t0 = blockIdx.x * 16;
    const int tid = threadIdx.x, wv = tid >> 6, lane = tid & 63;
    const int c = lane & 15, g = lane >> 4;
    const int colp = wv * 16 + c;

    // early: preload attn-proj weight frags (global, no dependencies)
    bf16x8 wap[8];
    {
        const ushort* wp = wb_ap + (size_t)colp * 256 + g * 8;
#pragma unroll
        for (int kc = 0; kc < 8; ++kc) wap[kc] = *(const bf16x8*)(wp + kc * 32);
    }

    {   // combine O quarters (ushort4 per thread)
        const int r = tid >> 6, c0 = (tid & 63) * 4;
        const int h = (tid & 63) >> 3;   // c0>>5: head of these 4 channels
        const float* lp = lpart + (size_t)(t0 + r) * 32;
        const float inv = 1.0f / (lp[h] + lp[8 + h] + lp[16 + h] + lp[24 + h]);
        const size_t idx = (size_t)(t0 + r) * 256 + c0;
        const ushort4 a = *(const ushort4*)(o1 + idx);
        const ushort4 b = *(const ushort4*)(o2 + idx);
        const ushort4 d = *(const ushort4*)(o3 + idx);
        const ushort4 e = *(const ushort4*)(o4 + idx);
        unsigned w[2];
        w[0] = pk_bf16((bf2f(a.x) + bf2f(b.x) + bf2f(d.x) + bf2f(e.x)) * inv,
                       (bf2f(a.y) + bf2f(b.y) + bf2f(d.y) + bf2f(e.y)) * inv);
        w[1] = pk_bf16((bf2f(a.z) + bf2f(b.z) + bf2f(d.z) + bf2f(e.z)) * inv,
                       (bf2f(a.w) + bf2f(b.w) + bf2f(d.w) + bf2f(e.w)) * inv);
        *(ushort4*)&Otile[r * 264 + c0] = *(ushort4*)w;
    }
    // issue ysum loads early — consumed after the AP-MFMA phase (T14)
    float ysv[4];
#pragma unroll
    for (int rr = 0; rr < 4; ++rr)
        ysv[rr] = ysum[(size_t)(t0 + 4 * g + rr) * 256 + colp];
    __syncthreads();

    // ---- attn-proj: wave w -> cols [16w,16w+16), one frag ----
    f32x4 accp = {};
#pragma unroll
    for (int kc = 0; kc < 8; ++kc) {
        const bf16x8 af = *(const bf16x8*)&Otile[c * 264 + kc * 32 + g * 8];
        accp = MFMA16(af, wap[kc], accp);
    }
    float vsave[4];
    {
        const float bb = b_ap[colp];
        float s1[4], s2[4];
#pragma unroll
        for (int rr = 0; rr < 4; ++rr) {
            const float v = accp[rr] + bb + ysv[rr];
            vsave[rr] = v; s1[rr] = v; s2[rr] = v * v;
        }
#pragma unroll
        for (int rr = 0; rr < 4; ++rr) { s1[rr] = rowsum16(s1[rr]); s2[rr] = rowsum16(s2[rr]); }
        if (c == 0) {
#pragma unroll
            for (int rr = 0; rr < 4; ++rr) {
                red[wv][4 * g + rr][0] = s1[rr];
                red[wv][4 * g + rr][1] = s2[rr];
            }
        }
        __syncthreads();
        if (tid < 32) {
            const int row = tid >> 1, j = tid & 1;
            float s = 0.f;
#pragma unroll
            for (int w = 0; w < 16; ++w) s += red[w][row][j];
            red[0][row][j] = s;
        }
        __syncthreads();
        const float gg = ln2_g[colp], lb = ln2_b[colp];
#pragma unroll
        for (int rr = 0; rr < 4; ++rr) {
            const int row = 4 * g + rr;
            const float mu = red[0][row][0] * (1.0f / 256.0f);
            const float var = red[0][row][1] * (1.0f / 256.0f) - mu * mu;
            const float rs = rsqrtf(var + EPSF);
            const float zv = (vsave[rr] - mu) * rs * gg + lb;
            Ztile[row * 264 + colp] = (ushort)f2bf(zv);
        }
    }
    __syncthreads();

    // ---- FF1 + gelu: wave w -> cols [64w,64w+64); weights preloaded 8-deep
    //      per output-frag (one L2 latency per nf) ----
    {
        const ushort* wf1 = wb_ff1 + (size_t)(wv * 64 + c) * 256 + g * 8;
        f32x4 accf[4] = {};
#pragma unroll
        for (int nf = 0; nf < 4; ++nf) {
            bf16x8 wf[8];
#pragma unroll
            for (int kc = 0; kc < 8; ++kc)
                wf[kc] = *(const bf16x8*)(wf1 + (size_t)nf * 4096 + kc * 32);
#pragma unroll
            for (int kc = 0; kc < 8; ++kc) {
                const bf16x8 af = *(const bf16x8*)&Ztile[c * 264 + kc * 32 + g * 8];
                accf[nf] = MFMA16(af, wf[kc], accf[nf]);
            }
        }
#pragma unroll
        for (int nf = 0; nf < 4; ++nf) {
            const int col = wv * 64 + nf * 16 + c;
            const float bb = b_ff1[col];
#pragma unroll
            for (int rr = 0; rr < 4; ++rr) {
                const float v = gelu_f(accf[nf][rr] + bb);
                Zbig[(4 * g + rr) * 1032 + col] = (ushort)f2bf(v);
            }
        }
    }
    __syncthreads();

    // ---- FF2: K=1024, weights preloaded 8-deep per chunk, 2 acc chains ----
    {
        const ushort* wf2 = wb_ff2 + (size_t)colp * 1024 + g * 8;
        f32x4 acc0 = {}, acc1 = {};
#pragma unroll
        for (int ch = 0; ch < 4; ++ch) {
            bf16x8 wf[8];
#pragma unroll
            for (int kk = 0; kk < 8; ++kk)
                wf[kk] = *(const bf16x8*)(wf2 + (ch * 8 + kk) * 32);
#pragma unroll
            for (int kk = 0; kk < 8; ++kk) {
                const int kc = ch * 8 + kk;
                const bf16x8 af = *(const bf16x8*)&Zbig[c * 1032 + kc * 32 + g * 8];
                if (kk & 1) acc1 = MFMA16(af, wf[kk], acc1);
                else        acc0 = MFMA16(af, wf[kk], acc0);
            }
        }
        const float bb = b_ff2[colp];
#pragma unroll
        for (int rr = 0; rr < 4; ++rr) {
            const float v = acc0[rr] + acc1[rr] + bb + vsave[rr];
            T2tile[(4 * g + rr) * 264 + colp] = (ushort)f2bf(v);
        }
    }
    // preload proj_out weights + x residual before the last barrier (T14)
    bf16x8 wout[8];
    {
        const ushort* wo = wb_out + (size_t)colp * 256 + g * 8;
#pragma unroll
        for (int kc = 0; kc < 8; ++kc) wout[kc] = *(const bf16x8*)(wo + kc * 32);
    }
    float xres[4];
#pragma unroll
    for (int rr = 0; rr < 4; ++rr)
        xres[rr] = x[(size_t)(wv * 16 + 4 * g + rr) * T_TOK + t0 + c];
    __syncthreads();

    // ---- proj_out: wave w -> out rows [16w,16w+16) ----
    f32x4 acco = {};
#pragma unroll
    for (int kc = 0; kc < 8; ++kc) {
        const bf16x8 bfr = *(const bf16x8*)&T2tile[c * 264 + kc * 32 + g * 8]; // B: token=c
        acco = MFMA16(wout[kc], bfr, acco);
    }
#pragma unroll
    for (int rr = 0; rr < 4; ++rr) {
        const int och = wv * 16 + 4 * g + rr;
        const size_t idx = (size_t)och * T_TOK + t0 + c;
        out[idx] = acco[rr] + b_out[och] + xres[rr];
    }
}

// ---------------------------------------------------------------------------
extern "C" void kernel_launch(void* const* d_in, const int* in_sizes, int n_in,
                              void* d_out, int out_size, void* d_ws, size_t ws_size,
                              hipStream_t stream)
{
    const float* x     = (const float*)d_in[0];
    const float* bn_g  = (const float*)d_in[1];
    const float* bn_b  = (const float*)d_in[2];
    const float* bn_m  = (const float*)d_in[3];
    const float* bn_v  = (const float*)d_in[4];
    const float* w_in  = (const float*)d_in[5];
    const float* b_in  = (const float*)d_in[6];
    const float* ln1_g = (const float*)d_in[7];
    const float* ln1_b = (const float*)d_in[8];
    const float* w_qkv = (const float*)d_in[9];
    const float* b_qkv = (const float*)d_in[10];
    const float* w_ap  = (const float*)d_in[11];
    const float* b_ap  = (const float*)d_in[12];
    const float* ln2_g = (const float*)d_in[13];
    const float* ln2_b = (const float*)d_in[14];
    const float* w_ff1 = (const float*)d_in[15];
    const float* b_ff1 = (const float*)d_in[16];
    const float* w_ff2 = (const float*)d_in[17];
    const float* b_ff2 = (const float*)d_in[18];
    const float* w_out = (const float*)d_in[19];
    const float* b_out = (const float*)d_in[20];
    float* out = (float*)d_out;
    float* ws  = (float*)d_ws;

    const size_t MF = 1u << 20;   // 1M f32 = 4 MB
    float*  ysum   = ws + MF;                           // [1M,2M)
    ushort* qkv_bf = (ushort*)(ws + 3 * MF);            // [3M,4.5M)
    ushort* o1p    = (ushort*)(ws + 6 * MF + MF / 2);   // [6.5M,7M)
    ushort* o2p    = (ushort*)(ws + 7 * MF);            // [7M,7.5M)
    ushort* o3p    = (ushort*)(ws + 7 * MF + MF / 2);   // [7.5M,8M)
    ushort* o4p    = (ushort*)(ws + 8 * MF);            // [8M,8.5M)
    float*  lpart  = ws + 8 * MF + MF / 2;              // [8.5M,+128K f32 = 512KB)
    ushort* wbuf   = (ushort*)(ws + 8 * MF + MF / 2 + 131072);  // weight arena
    const ushort* wb_in  = wbuf;
    const ushort* wb_qkv = wbuf + 65536;
    const ushort* wb_ap  = wbuf + 262144;
    const ushort* wb_ff1 = wbuf + 327680;
    const ushort* wb_ff2 = wbuf + 589824;
    const ushort* wb_out = wbuf + 851968;
    float* bqs = (float*)(wbuf + 917504);

    prep_kernel<<<896, 256, 0, stream>>>(w_in, w_qkv, w_ap, w_ff1, w_ff2, w_out,
                                         b_qkv, wbuf, bqs);
    fused_pre<<<256, 1024, 0, stream>>>(x, bn_g, bn_b, bn_m, bn_v,
                                        wb_in, b_in, ln1_g, ln1_b,
                                        wb_qkv, bqs, ysum, qkv_bf);
    attn_mfma<<<dim3(32, 8, 4), 256, 0, stream>>>(qkv_bf, o1p, o2p, o3p, o4p, lpart);
    fused_tail<<<256, 1024, 0, stream>>>(o1p, o2p, o3p, o4p, lpart, wb_ap, b_ap,
                                         ysum, ln2_g, ln2_b, wb_ff1, b_ff1,
                                         wb_ff2, b_ff2, wb_out, b_out, x, out);
}